// Round 12
// baseline (706.701 us; speedup 1.0000x reference)
//
#include <hip/hip_runtime.h>

#define DH 64
#define DIN 32
#define BSH 8                 // bucket = dst >> 8 (256-node ranges)
#define BNODES 256
#define MAXB 1024
#define CAPSH 13              // per-bucket capacity 8192 (avg fill ~4.1k, sigma ~64)
#define CAP (1 << CAPSH)

typedef unsigned short u16;
typedef unsigned int u32;
typedef float f32x2 __attribute__((ext_vector_type(2)));

__device__ __forceinline__ float bf2f(u16 u) {
    union { u32 i; float f; } x; x.i = ((u32)u) << 16; return x.f;
}
__device__ __forceinline__ u16 f2bf(float f) {
    union { float f; u32 i; } x; x.f = f;
    u32 r = x.i + 0x7fff + ((x.i >> 16) & 1);    // round-to-nearest-even
    return (u16)(r >> 16);
}
// unpack low/high bf16 of a u32 (2 packed bf16) to f32
__device__ __forceinline__ float bfl(u32 u) {
    union { u32 i; float f; } x; x.i = u << 16; return x.f;
}
__device__ __forceinline__ float bfh(u32 u) {
    union { u32 i; float f; } x; x.i = u & 0xffff0000u; return x.f;
}
// packed-f32 accumulate of 2 bf16 lanes: a += {bfl(u), bfh(u)}
__device__ __forceinline__ void pkacc(f32x2& a, u32 u) {
    f32x2 b;
    b[0] = bfl(u); b[1] = bfh(u);
    asm("v_pk_add_f32 %0, %1, %0" : "+v"(a) : "v"(b));
}

// bin packed (src<<BSH | local_dst) into fixed-capacity bucket spans with
// per-(block,bucket) private sub-spans. Grid-stride granules.
// 256 blocks x 1024 thr: ~16 edges = 64B block-private sectors (R7's
// false-sharing lesson: keep spans >= one 64B sector and block-private).
__global__ void __launch_bounds__(1024) binA_k(
        const int* __restrict__ ei, int* __restrict__ gcnt,
        u32* __restrict__ pairs, int E, int n, int nbuck) {
    __shared__ int lhist[MAXB];
    __shared__ int lbase[MAXB];
    __shared__ int smode;
    int t = threadIdx.x;
    if (t < 64) {   // int64 layout: odd 32-bit words are zero high-words
        int v = (2 * t + 1 < 2 * E) ? ei[2 * t + 1] : 0;
        unsigned long long b = __ballot(v != 0);
        if (t == 0) smode = (b != 0ULL) ? 1 : 0;
    }
    for (int b = t; b < nbuck; b += 1024) lhist[b] = 0;
    __syncthreads();
    int m = smode;
    unsigned un = (unsigned)n;
    int q0 = blockIdx.x * 1024 + t;
    int qs = gridDim.x * 1024;

    // ---- phase 1: count this block's edges per bucket
    if (m && !(E & 3)) {                       // int32, 4 edges per int4
        const int4* d4 = (const int4*)(ei + E);
        for (int q = q0; q < (E >> 2); q += qs) {
            int4 d = d4[q];
            if ((unsigned)d.x < un) atomicAdd(&lhist[d.x >> BSH], 1);
            if ((unsigned)d.y < un) atomicAdd(&lhist[d.y >> BSH], 1);
            if ((unsigned)d.z < un) atomicAdd(&lhist[d.z >> BSH], 1);
            if ((unsigned)d.w < un) atomicAdd(&lhist[d.w >> BSH], 1);
        }
    } else if (!m && !(E & 1)) {               // int64, 2 edges per int4
        const int4* d4 = (const int4*)(ei + 2 * E);
        for (int q = q0; q < (E >> 1); q += qs) {
            int4 d = d4[q];
            if ((unsigned)d.x < un) atomicAdd(&lhist[d.x >> BSH], 1);
            if ((unsigned)d.z < un) atomicAdd(&lhist[d.z >> BSH], 1);
        }
    } else {
        const int* dstp = m ? (ei + E) : (ei + 2 * E);
        int stride = m ? 1 : 2;
        for (int e = q0; e < E; e += qs) {
            int d = dstp[(size_t)e * stride];
            if ((unsigned)d < un) atomicAdd(&lhist[d >> BSH], 1);
        }
    }
    __syncthreads();
    // ---- phase 2: reserve private spans
    for (int b = t; b < nbuck; b += 1024) {
        int c = lhist[b];
        lbase[b] = c ? ((b << CAPSH) + atomicAdd(&gcnt[b], c)) : 0;
        lhist[b] = 0;                          // reuse as local cursor
    }
    __syncthreads();
    // ---- phase 3: scatter into private spans
    #define EMIT(S, D)                                                     \
        if ((unsigned)(D) < un) {                                          \
            int sv = ((unsigned)(S) < un) ? (S) : 0;                       \
            int bb = (D) >> BSH;                                           \
            int off = atomicAdd(&lhist[bb], 1);                            \
            int pos = lbase[bb] + off;                                     \
            if (pos < ((bb + 1) << CAPSH))                                 \
                pairs[pos] = ((u32)sv << BSH) | (u32)((D) & (BNODES - 1)); \
        }
    if (m && !(E & 3)) {
        const int4* s4 = (const int4*)ei;
        const int4* d4 = (const int4*)(ei + E);
        for (int q = q0; q < (E >> 2); q += qs) {
            int4 s = s4[q]; int4 d = d4[q];
            EMIT(s.x, d.x) EMIT(s.y, d.y) EMIT(s.z, d.z) EMIT(s.w, d.w)
        }
    } else if (!m && !(E & 1)) {
        const int4* s4 = (const int4*)ei;
        const int4* d4 = (const int4*)(ei + 2 * E);
        for (int q = q0; q < (E >> 1); q += qs) {
            int4 s = s4[q]; int4 d = d4[q];
            EMIT(s.x, d.x) EMIT(s.z, d.z)
        }
    } else {
        const int* srcp = ei;
        const int* dstp = m ? (ei + E) : (ei + 2 * E);
        int stride = m ? 1 : 2;
        for (int e = q0; e < E; e += qs) {
            int d = dstp[(size_t)e * stride];
            int s = srcp[(size_t)e * stride];
            EMIT(s, d)
        }
    }
    #undef EMIT
}

// one block (1024 thr) per bucket: CSR build, two-pass (R10-proven).
// col[] = pre-shifted byte offsets (src*128); rse[node] = {start,end}.
// Degree histogram (64 clamped bins) folded in — feeds the degree-sorted
// node remap (dscat_k) at zero extra passes.
__global__ void __launch_bounds__(1024) csr_build_k(
        const u32* __restrict__ pairs, const int* __restrict__ gcnt,
        int2* __restrict__ rse,
        int* __restrict__ col, float* __restrict__ dinv,
        int* __restrict__ dhist, int N) {
    __shared__ int cnt[BNODES];
    __shared__ int s[BNODES];
    int b = blockIdx.x, t = threadIdx.x;
    int base = b << CAPSH;
    int ec = gcnt[b]; if (ec > CAP) ec = CAP;
    int end = base + ec;
    if (t < BNODES) cnt[t] = 0;
    __syncthreads();
    for (int i = base + t; i < end; i += 1024)
        atomicAdd(&cnt[pairs[i] & (BNODES - 1)], 1);
    __syncthreads();
    int v = (t < BNODES) ? cnt[t] : 0;
    if (t < BNODES) s[t] = v;
    __syncthreads();
    for (int off = 1; off < BNODES; off <<= 1) {
        int xsc = (t >= off && t < BNODES) ? s[t - off] : 0;
        __syncthreads();
        if (t < BNODES) s[t] += xsc;
        __syncthreads();
    }
    if (t < BNODES) {
        int excl = s[t] - v;
        int a = base + excl;
        int node = (b << BSH) + t;
        if (node < N) {
            rse[node]  = make_int2(a, a + v);
            dinv[node] = rsqrtf((float)v + 1.0f);
            atomicAdd(&dhist[v > 63 ? 63 : v], 1);
        }
        cnt[t] = a;                            // cursor
    }
    __syncthreads();
    for (int i = base + t; i < end; i += 1024) {
        u32 p = pairs[i];
        int pos = atomicAdd(&cnt[p & (BNODES - 1)], 1);
        col[pos] = (int)((p >> BSH) << 7);     // byte offset = src * 128
    }
}

// degree-sort scatter: nmap = node ids sorted by (clamped) degree.
// Each block redundantly scans the 64-bin dhist (cheap) and scatters via
// zero-initialized global cursors dcnt2. Per-node results are bit-identical
// regardless of intra-bin order — nmap only changes wave grouping.
__global__ void __launch_bounds__(256) dscat_k(
        const int2* __restrict__ rse, const int* __restrict__ dhist,
        int* __restrict__ dcnt2, int* __restrict__ nmap, int N) {
    __shared__ int dbase[64];
    int t = threadIdx.x;
    if (t < 64) {
        int v = dhist[t];
        int x = v;
        for (int off = 1; off < 64; off <<= 1) {
            int y = __shfl_up(x, off, 64);
            if (t >= off) x += y;
        }
        dbase[t] = x - v;                     // exclusive prefix
    }
    __syncthreads();
    int i = blockIdx.x * 256 + t;
    if (i < N) {
        int2 se = rse[i];
        int d = se.y - se.x; if (d > 63) d = 63;
        int pos = dbase[d] + atomicAdd(&dcnt2[d], 1);
        nmap[pos] = i;
    }
}

// full-grid layer-1 transform: h1' = (x @ W1) * dinv -> bf16 rows into hp
// (hp aliases the pairs buffer; safe across the kernel boundary).
__global__ void __launch_bounds__(256) gemm1_k(
        const float* __restrict__ x, const float* __restrict__ W1,
        const float* __restrict__ dinv, u16* __restrict__ hp, int N) {
    __shared__ float Wl[DIN * DH];           // 8 KB
    __shared__ float xl[16][DIN + 4];        // 2.3 KB
    int t = threadIdx.x;
    {
        const float4* Wv = (const float4*)W1;
        float4* Wd = (float4*)Wl;
        #pragma unroll
        for (int r = 0; r < 2; r++) Wd[t + 256 * r] = Wv[t + 256 * r];
    }
    // zero hp sentinel row (index N): read by agg_gemm_k's sentinel gathers.
    if (blockIdx.x == 0 && t < 32)
        ((float*)(hp + (size_t)N * DH))[t] = 0.f;
    if (t < 128) {
        int row = t >> 3, ck = (t & 7) * 4;
        int node = blockIdx.x * 16 + row;
        float4 vx = {0.f, 0.f, 0.f, 0.f};
        if (node < N)
            vx = *(const float4*)&x[(size_t)node * DIN + ck];
        *(float4*)&xl[row][ck] = vx;
    }
    __syncthreads();
    int lane = t & 63, w = t >> 6;
    int g = lane >> 4, c = lane & 15;
    int nl = w * 4 + g;
    int node = blockIdx.x * 16 + nl;
    const float* xr = xl[nl];
    float4 acc = {0.f, 0.f, 0.f, 0.f};
    #pragma unroll
    for (int k = 0; k < DIN; k++) {
        float xv = xr[k];
        float4 wv = *(const float4*)&Wl[k * DH + c * 4];
        acc.x += xv * wv.x; acc.y += xv * wv.y; acc.z += xv * wv.z; acc.w += xv * wv.w;
    }
    if (node < N) {
        float di = dinv[node];
        ushort4 o;
        o.x = f2bf(acc.x * di); o.y = f2bf(acc.y * di);
        o.z = f2bf(acc.z * di); o.w = f2bf(acc.w * di);
        *(ushort4*)&hp[(size_t)node * DH + c * 4] = o;
    }
}

// group-per-node edge sum, 8-lane groups: lane c (0..7) owns 8 columns (16B).
// ROLLING depth-8 (R9/R10-proven): accumulate v[j] (oldest) then immediately
// reissue v[j] for the next chunk -> ~8-14 loads in flight with only 32
// buffer VGPRs. Byte-offset cols, folded lane offset, sentinel row.
// Per-column accumulation order is edge-ascending.
__device__ __forceinline__ void edge_sum_roll8(const u16* __restrict__ hp,
                                               const int* __restrict__ colb,
                                               int start, int deg, int gl, int c,
                                               int sentb, f32x2* __restrict__ acc) {
    int dm = deg;                              // wave-uniform max degree
    dm = max(dm, __shfl_xor(dm, 8, 64));
    dm = max(dm, __shfl_xor(dm, 16, 64));
    dm = max(dm, __shfl_xor(dm, 32, 64));
    if (dm <= 0) return;
    const char* hpco = (const char*)hp + ((u32)c << 4);
    int nch = (dm + 7) >> 3;
    uint4 v0, v1, v2, v3, v4, v5, v6, v7;
    int cb = (c < deg) ? colb[start + c] : sentb;     // chunk 0 col slice
    {   // prologue: issue chunk 0
        int s;
        s = __shfl(cb, gl | 0, 64); v0 = *(const uint4*)(hpco + s);
        s = __shfl(cb, gl | 1, 64); v1 = *(const uint4*)(hpco + s);
        s = __shfl(cb, gl | 2, 64); v2 = *(const uint4*)(hpco + s);
        s = __shfl(cb, gl | 3, 64); v3 = *(const uint4*)(hpco + s);
        s = __shfl(cb, gl | 4, 64); v4 = *(const uint4*)(hpco + s);
        s = __shfl(cb, gl | 5, 64); v5 = *(const uint4*)(hpco + s);
        s = __shfl(cb, gl | 6, 64); v6 = *(const uint4*)(hpco + s);
        s = __shfl(cb, gl | 7, 64); v7 = *(const uint4*)(hpco + s);
    }
    int cbn = (8 + c < deg) ? colb[start + 8 + c] : sentb;   // chunk 1 cols
    for (int ch = 1; ch < nch; ch++) {
        int cbu = cbn;
        int nb2 = (ch + 1) << 3;
        cbn = (nb2 + c < deg) ? colb[start + nb2 + c] : sentb;  // prefetch ahead
        int s;
        s = __shfl(cbu, gl | 0, 64);
        pkacc(acc[0], v0.x); pkacc(acc[1], v0.y); pkacc(acc[2], v0.z); pkacc(acc[3], v0.w);
        v0 = *(const uint4*)(hpco + s);
        s = __shfl(cbu, gl | 1, 64);
        pkacc(acc[0], v1.x); pkacc(acc[1], v1.y); pkacc(acc[2], v1.z); pkacc(acc[3], v1.w);
        v1 = *(const uint4*)(hpco + s);
        s = __shfl(cbu, gl | 2, 64);
        pkacc(acc[0], v2.x); pkacc(acc[1], v2.y); pkacc(acc[2], v2.z); pkacc(acc[3], v2.w);
        v2 = *(const uint4*)(hpco + s);
        s = __shfl(cbu, gl | 3, 64);
        pkacc(acc[0], v3.x); pkacc(acc[1], v3.y); pkacc(acc[2], v3.z); pkacc(acc[3], v3.w);
        v3 = *(const uint4*)(hpco + s);
        s = __shfl(cbu, gl | 4, 64);
        pkacc(acc[0], v4.x); pkacc(acc[1], v4.y); pkacc(acc[2], v4.z); pkacc(acc[3], v4.w);
        v4 = *(const uint4*)(hpco + s);
        s = __shfl(cbu, gl | 5, 64);
        pkacc(acc[0], v5.x); pkacc(acc[1], v5.y); pkacc(acc[2], v5.z); pkacc(acc[3], v5.w);
        v5 = *(const uint4*)(hpco + s);
        s = __shfl(cbu, gl | 6, 64);
        pkacc(acc[0], v6.x); pkacc(acc[1], v6.y); pkacc(acc[2], v6.z); pkacc(acc[3], v6.w);
        v6 = *(const uint4*)(hpco + s);
        s = __shfl(cbu, gl | 7, 64);
        pkacc(acc[0], v7.x); pkacc(acc[1], v7.y); pkacc(acc[2], v7.z); pkacc(acc[3], v7.w);
        v7 = *(const uint4*)(hpco + s);
    }
    // drain final chunk
    pkacc(acc[0], v0.x); pkacc(acc[1], v0.y); pkacc(acc[2], v0.z); pkacc(acc[3], v0.w);
    pkacc(acc[0], v1.x); pkacc(acc[1], v1.y); pkacc(acc[2], v1.z); pkacc(acc[3], v1.w);
    pkacc(acc[0], v2.x); pkacc(acc[1], v2.y); pkacc(acc[2], v2.z); pkacc(acc[3], v2.w);
    pkacc(acc[0], v3.x); pkacc(acc[1], v3.y); pkacc(acc[2], v3.z); pkacc(acc[3], v3.w);
    pkacc(acc[0], v4.x); pkacc(acc[1], v4.y); pkacc(acc[2], v4.z); pkacc(acc[3], v4.w);
    pkacc(acc[0], v5.x); pkacc(acc[1], v5.y); pkacc(acc[2], v5.z); pkacc(acc[3], v5.w);
    pkacc(acc[0], v6.x); pkacc(acc[1], v6.y); pkacc(acc[2], v6.z); pkacc(acc[3], v6.w);
    pkacc(acc[0], v7.x); pkacc(acc[1], v7.y); pkacc(acc[2], v7.z); pkacc(acc[3], v7.w);
}

// FUSED layer-1 aggregation + layer-2 GEMM: roll8 gather + xs-LDS epilogue
// (R10-proven) + degree-sorted node remap: all 8 nodes of a wave have
// near-equal degree -> wave-max padding eliminated.
__global__ void __launch_bounds__(256) agg_gemm_k(
        const u16* __restrict__ hp, const int2* __restrict__ rse,
        const int* __restrict__ col, const int* __restrict__ nmap,
        const float* __restrict__ dinv, const float* __restrict__ b1,
        const float* __restrict__ W2, u16* __restrict__ hp2, int N) {
    __shared__ float Wl[DH * DH];            // 16 KB
    __shared__ float xs[4][8][DH + 4];       // 8.5 KB, group rows, 68-float stride
    int tid = threadIdx.x;
    {
        const float4* Wv = (const float4*)W2;
        float4* Wd = (float4*)Wl;
        #pragma unroll
        for (int r = 0; r < 4; r++) Wd[tid + 256 * r] = Wv[tid + 256 * r];
    }
    // zero hp2's sentinel row (read by agg_head_k next kernel; hp2 != hp)
    if (blockIdx.x == 0 && tid < 32)
        ((float*)(hp2 + (size_t)N * DH))[tid] = 0.f;
    __syncthreads();
    int lane = tid & 63, w = tid >> 6;
    int g = lane >> 3, c = lane & 7, gl = g << 3;
    int idx = blockIdx.x * 32 + w * 8 + g;
    int node = (idx < N) ? nmap[idx] : N;     // N -> deg 0, all guards false
    int start = 0, deg = 0;
    if (node < N) { int2 se = rse[node]; start = se.x; deg = se.y - se.x; }
    f32x2 acc[4] = {{0.f,0.f},{0.f,0.f},{0.f,0.f},{0.f,0.f}};
    edge_sum_roll8(hp, col, start, deg, gl, c, N << 7, acc);
    float di = (node < N) ? dinv[node] : 0.f;
    float o0=0.f,o1=0.f,o2=0.f,o3=0.f,o4=0.f,o5=0.f,o6=0.f,o7=0.f;
    if (node < N) {
        uint4 sv = *(const uint4*)&hp[(size_t)node * DH + c * 8];
        float4 blo = *(const float4*)&b1[c * 8];
        float4 bhi = *(const float4*)&b1[c * 8 + 4];
        o0 = fmaxf((acc[0][0] + bfl(sv.x)) * di + blo.x, 0.f);
        o1 = fmaxf((acc[0][1] + bfh(sv.x)) * di + blo.y, 0.f);
        o2 = fmaxf((acc[1][0] + bfl(sv.y)) * di + blo.z, 0.f);
        o3 = fmaxf((acc[1][1] + bfh(sv.y)) * di + blo.w, 0.f);
        o4 = fmaxf((acc[2][0] + bfl(sv.z)) * di + bhi.x, 0.f);
        o5 = fmaxf((acc[2][1] + bfh(sv.z)) * di + bhi.y, 0.f);
        o6 = fmaxf((acc[3][0] + bfl(sv.w)) * di + bhi.z, 0.f);
        o7 = fmaxf((acc[3][1] + bfh(sv.w)) * di + bhi.w, 0.f);
    }
    *(float4*)&xs[w][g][c * 8]     = make_float4(o0, o1, o2, o3);  // same-wave
    *(float4*)&xs[w][g][c * 8 + 4] = make_float4(o4, o5, o6, o7);  // produce/consume
    const float* xr = xs[w][g];
    float4 alo = {0.f,0.f,0.f,0.f}, ahi = {0.f,0.f,0.f,0.f};
    #pragma unroll
    for (int k4 = 0; k4 < DH / 4; k4++) {
        float4 xv4 = *(const float4*)&xr[k4 * 4];
        float xj[4] = {xv4.x, xv4.y, xv4.z, xv4.w};
        #pragma unroll
        for (int j = 0; j < 4; j++) {
            const float* wr = &Wl[(k4 * 4 + j) * DH + c * 8];
            float4 w0 = *(const float4*)wr;
            float4 w1 = *(const float4*)(wr + 4);
            float xv = xj[j];
            alo.x += xv * w0.x; alo.y += xv * w0.y; alo.z += xv * w0.z; alo.w += xv * w0.w;
            ahi.x += xv * w1.x; ahi.y += xv * w1.y; ahi.z += xv * w1.z; ahi.w += xv * w1.w;
        }
    }
    if (node < N) {
        uint4 po;
        po.x = (u32)f2bf(alo.x * di) | ((u32)f2bf(alo.y * di) << 16);
        po.y = (u32)f2bf(alo.z * di) | ((u32)f2bf(alo.w * di) << 16);
        po.z = (u32)f2bf(ahi.x * di) | ((u32)f2bf(ahi.y * di) << 16);
        po.w = (u32)f2bf(ahi.z * di) | ((u32)f2bf(ahi.w * di) << 16);
        *(uint4*)&hp2[(size_t)node * DH + c * 8] = po;
    }
}

// fused layer-2 aggregation + head: y = sigmoid(relu(out2) . Wo + bo)
// roll8 gather + degree-sorted node remap.
__global__ void __launch_bounds__(256) agg_head_k(
        const u16* __restrict__ hp, const int2* __restrict__ rse,
        const int* __restrict__ col, const int* __restrict__ nmap,
        const float* __restrict__ dinv, const float* __restrict__ bias,
        const float* __restrict__ Wo, const float* __restrict__ bo,
        float* __restrict__ y, int N) {
    int lane = threadIdx.x & 63;
    int g = lane >> 3, c = lane & 7, gl = g << 3;
    int idx = blockIdx.x * 32 + (threadIdx.x >> 6) * 8 + g;
    int node = (idx < N) ? nmap[idx] : N;
    int start = 0, deg = 0;
    if (node < N) { int2 se = rse[node]; start = se.x; deg = se.y - se.x; }
    f32x2 acc[4] = {{0.f,0.f},{0.f,0.f},{0.f,0.f},{0.f,0.f}};
    edge_sum_roll8(hp, col, start, deg, gl, c, N << 7, acc);
    float t = 0.f;
    if (node < N) {
        uint4 sv = *(const uint4*)&hp[(size_t)node * DH + c * 8];
        float4 blo = *(const float4*)&bias[c * 8];
        float4 bhi = *(const float4*)&bias[c * 8 + 4];
        float4 wlo = *(const float4*)&Wo[c * 8];
        float4 whi = *(const float4*)&Wo[c * 8 + 4];
        float di = dinv[node];
        t = fmaxf((acc[0][0] + bfl(sv.x)) * di + blo.x, 0.f) * wlo.x
          + fmaxf((acc[0][1] + bfh(sv.x)) * di + blo.y, 0.f) * wlo.y
          + fmaxf((acc[1][0] + bfl(sv.y)) * di + blo.z, 0.f) * wlo.z
          + fmaxf((acc[1][1] + bfh(sv.y)) * di + blo.w, 0.f) * wlo.w
          + fmaxf((acc[2][0] + bfl(sv.z)) * di + bhi.x, 0.f) * whi.x
          + fmaxf((acc[2][1] + bfh(sv.z)) * di + bhi.y, 0.f) * whi.y
          + fmaxf((acc[3][0] + bfl(sv.w)) * di + bhi.z, 0.f) * whi.z
          + fmaxf((acc[3][1] + bfh(sv.w)) * di + bhi.w, 0.f) * whi.w;
    }
    t += __shfl_xor(t, 1, 64);
    t += __shfl_xor(t, 2, 64);
    t += __shfl_xor(t, 4, 64);
    if (c == 0 && node < N) {
        float z = t + bo[0];
        y[node] = 1.f / (1.f + __expf(-z));
    }
}

extern "C" void kernel_launch(void* const* d_in, const int* in_sizes, int n_in,
                              void* d_out, int out_size, void* d_ws, size_t ws_size,
                              hipStream_t stream) {
    const float* x  = (const float*)d_in[0];
    const int*   ei = (const int*)d_in[1];
    const float* W1 = (const float*)d_in[2];
    const float* b1 = (const float*)d_in[3];
    const float* W2 = (const float*)d_in[4];
    const float* b2 = (const float*)d_in[5];
    const float* Wo = (const float*)d_in[6];
    const float* bo = (const float*)d_in[7];
    float* y = (float*)d_out;

    int N = in_sizes[0] / DIN;
    int E = in_sizes[1] / 2;
    int nbuck = ((N - 1) >> BSH) + 1;            // 391 for N=100k (<= MAXB)

    char* ws = (char*)d_ws;
    size_t off = 0;
    auto alloc = [&](size_t bytes) { char* p = ws + off; off += (bytes + 255) & ~(size_t)255; return p; };
    int*   gcnt   = (int*)alloc((MAXB + 128) * 4);   // + dhist[64] + dcnt2[64]
    int*   dhist  = gcnt + MAXB;
    int*   dcnt2  = gcnt + MAXB + 64;
    int2*  rse    = (int2*)alloc((size_t)N * 8);
    float* dinv   = (float*)alloc((size_t)N * 4);
    int*   nmap   = (int*)alloc((size_t)N * 4);
    int*   col    = (int*)alloc(((size_t)nbuck << CAPSH) * 4);   // ~12.8 MB
    size_t pair_b = ((size_t)nbuck << CAPSH) * 4;
    size_t hp_b   = (size_t)N * DH * 2 + 256;                    // + zero sentinel row
    char*  bufA   = (char*)alloc(pair_b > hp_b ? pair_b : hp_b); // pairs / h1' alias
    u16*   bufB   = (u16*)alloc(hp_b);                           // h2' bf16 + sentinel
    u16*   hp    = (u16*)bufA;
    u32*   pairs = (u32*)bufA;

    hipMemsetAsync(gcnt, 0, (size_t)(MAXB + 128) * 4, stream);
    binA_k<<<256, 1024, 0, stream>>>(ei, gcnt, pairs, E, N, nbuck);
    // CSR build (pairs consumed; col = byte offsets; degree hist folded in)
    csr_build_k<<<nbuck, 1024, 0, stream>>>(pairs, gcnt, rse, col, dinv, dhist, N);
    // degree-sorted node remap
    dscat_k<<<(N + 255) / 256, 256, 0, stream>>>(rse, dhist, dcnt2, nmap, N);
    // full-grid layer-1 transform (overwrites pairs span with h1' bf16)
    gemm1_k<<<(N + 15) / 16, 256, 0, stream>>>(x, W1, dinv, hp, N);
    // layer-1 aggregation fused with layer-2 transform: bufB = h2'
    agg_gemm_k<<<(N + 31) / 32, 256, 0, stream>>>(hp, rse, col, nmap, dinv, b1, W2, bufB, N);
    // layer-2 aggregation fused with head
    agg_head_k<<<(N + 31) / 32, 256, 0, stream>>>(bufB, rse, col, nmap, dinv, b2, Wo, bo, y, N);
}

// Round 13
// 198.592 us; speedup vs baseline: 3.5586x; 3.5586x over previous
//
#include <hip/hip_runtime.h>

#define DH 64
#define DIN 32
#define BSH 8                 // bucket = dst >> 8 (256-node ranges)
#define BNODES 256
#define MAXB 1024
#define CAPSH 13              // per-bucket capacity 8192 (avg fill ~4.1k, sigma ~64)
#define CAP (1 << CAPSH)

typedef unsigned short u16;
typedef unsigned int u32;
typedef float f32x2 __attribute__((ext_vector_type(2)));

__device__ __forceinline__ float bf2f(u16 u) {
    union { u32 i; float f; } x; x.i = ((u32)u) << 16; return x.f;
}
__device__ __forceinline__ u16 f2bf(float f) {
    union { float f; u32 i; } x; x.f = f;
    u32 r = x.i + 0x7fff + ((x.i >> 16) & 1);    // round-to-nearest-even
    return (u16)(r >> 16);
}
// unpack low/high bf16 of a u32 (2 packed bf16) to f32
__device__ __forceinline__ float bfl(u32 u) {
    union { u32 i; float f; } x; x.i = u << 16; return x.f;
}
__device__ __forceinline__ float bfh(u32 u) {
    union { u32 i; float f; } x; x.i = u & 0xffff0000u; return x.f;
}
// packed-f32 accumulate of 2 bf16 lanes: a += {bfl(u), bfh(u)}
__device__ __forceinline__ void pkacc(f32x2& a, u32 u) {
    f32x2 b;
    b[0] = bfl(u); b[1] = bfh(u);
    asm("v_pk_add_f32 %0, %1, %0" : "+v"(a) : "v"(b));
}

// bin packed (src<<BSH | local_dst) into fixed-capacity bucket spans with
// per-(block,bucket) private sub-spans. Grid-stride granules.
// 256 blocks x 1024 thr: ~16 edges = 64B block-private sectors (R7's
// false-sharing lesson: keep spans >= one 64B sector and block-private).
__global__ void __launch_bounds__(1024) binA_k(
        const int* __restrict__ ei, int* __restrict__ gcnt,
        u32* __restrict__ pairs, int E, int n, int nbuck) {
    __shared__ int lhist[MAXB];
    __shared__ int lbase[MAXB];
    __shared__ int smode;
    int t = threadIdx.x;
    if (t < 64) {   // int64 layout: odd 32-bit words are zero high-words
        int v = (2 * t + 1 < 2 * E) ? ei[2 * t + 1] : 0;
        unsigned long long b = __ballot(v != 0);
        if (t == 0) smode = (b != 0ULL) ? 1 : 0;
    }
    for (int b = t; b < nbuck; b += 1024) lhist[b] = 0;
    __syncthreads();
    int m = smode;
    unsigned un = (unsigned)n;
    int q0 = blockIdx.x * 1024 + t;
    int qs = gridDim.x * 1024;

    // ---- phase 1: count this block's edges per bucket
    if (m && !(E & 3)) {                       // int32, 4 edges per int4
        const int4* d4 = (const int4*)(ei + E);
        for (int q = q0; q < (E >> 2); q += qs) {
            int4 d = d4[q];
            if ((unsigned)d.x < un) atomicAdd(&lhist[d.x >> BSH], 1);
            if ((unsigned)d.y < un) atomicAdd(&lhist[d.y >> BSH], 1);
            if ((unsigned)d.z < un) atomicAdd(&lhist[d.z >> BSH], 1);
            if ((unsigned)d.w < un) atomicAdd(&lhist[d.w >> BSH], 1);
        }
    } else if (!m && !(E & 1)) {               // int64, 2 edges per int4
        const int4* d4 = (const int4*)(ei + 2 * E);
        for (int q = q0; q < (E >> 1); q += qs) {
            int4 d = d4[q];
            if ((unsigned)d.x < un) atomicAdd(&lhist[d.x >> BSH], 1);
            if ((unsigned)d.z < un) atomicAdd(&lhist[d.z >> BSH], 1);
        }
    } else {
        const int* dstp = m ? (ei + E) : (ei + 2 * E);
        int stride = m ? 1 : 2;
        for (int e = q0; e < E; e += qs) {
            int d = dstp[(size_t)e * stride];
            if ((unsigned)d < un) atomicAdd(&lhist[d >> BSH], 1);
        }
    }
    __syncthreads();
    // ---- phase 2: reserve private spans
    for (int b = t; b < nbuck; b += 1024) {
        int c = lhist[b];
        lbase[b] = c ? ((b << CAPSH) + atomicAdd(&gcnt[b], c)) : 0;
        lhist[b] = 0;                          // reuse as local cursor
    }
    __syncthreads();
    // ---- phase 3: scatter into private spans
    #define EMIT(S, D)                                                     \
        if ((unsigned)(D) < un) {                                          \
            int sv = ((unsigned)(S) < un) ? (S) : 0;                       \
            int bb = (D) >> BSH;                                           \
            int off = atomicAdd(&lhist[bb], 1);                            \
            int pos = lbase[bb] + off;                                     \
            if (pos < ((bb + 1) << CAPSH))                                 \
                pairs[pos] = ((u32)sv << BSH) | (u32)((D) & (BNODES - 1)); \
        }
    if (m && !(E & 3)) {
        const int4* s4 = (const int4*)ei;
        const int4* d4 = (const int4*)(ei + E);
        for (int q = q0; q < (E >> 2); q += qs) {
            int4 s = s4[q]; int4 d = d4[q];
            EMIT(s.x, d.x) EMIT(s.y, d.y) EMIT(s.z, d.z) EMIT(s.w, d.w)
        }
    } else if (!m && !(E & 1)) {
        const int4* s4 = (const int4*)ei;
        const int4* d4 = (const int4*)(ei + 2 * E);
        for (int q = q0; q < (E >> 1); q += qs) {
            int4 s = s4[q]; int4 d = d4[q];
            EMIT(s.x, d.x) EMIT(s.z, d.z)
        }
    } else {
        const int* srcp = ei;
        const int* dstp = m ? (ei + E) : (ei + 2 * E);
        int stride = m ? 1 : 2;
        for (int e = q0; e < E; e += qs) {
            int d = dstp[(size_t)e * stride];
            int s = srcp[(size_t)e * stride];
            EMIT(s, d)
        }
    }
    #undef EMIT
}

// one block (1024 thr) per bucket: CSR build, two-pass (R10-proven).
// col[] = pre-shifted byte offsets (src*128); rse[node] = {start,end}.
// Degree histogram via LDS (64 bins) + ONE global atomicAdd per bin per
// block — R12 lesson: per-node global atomics into 64 hot bins serialize
// at L2 (268us!). Per-bin global traffic is now 391 adds total.
__global__ void __launch_bounds__(1024) csr_build_k(
        const u32* __restrict__ pairs, const int* __restrict__ gcnt,
        int2* __restrict__ rse,
        int* __restrict__ col, float* __restrict__ dinv,
        int* __restrict__ dhist, int N) {
    __shared__ int cnt[BNODES];
    __shared__ int s[BNODES];
    __shared__ int ldh[64];
    int b = blockIdx.x, t = threadIdx.x;
    int base = b << CAPSH;
    int ec = gcnt[b]; if (ec > CAP) ec = CAP;
    int end = base + ec;
    if (t < BNODES) cnt[t] = 0;
    if (t < 64) ldh[t] = 0;
    __syncthreads();
    for (int i = base + t; i < end; i += 1024)
        atomicAdd(&cnt[pairs[i] & (BNODES - 1)], 1);
    __syncthreads();
    int v = (t < BNODES) ? cnt[t] : 0;
    if (t < BNODES) s[t] = v;
    __syncthreads();
    for (int off = 1; off < BNODES; off <<= 1) {
        int xsc = (t >= off && t < BNODES) ? s[t - off] : 0;
        __syncthreads();
        if (t < BNODES) s[t] += xsc;
        __syncthreads();
    }
    if (t < BNODES) {
        int excl = s[t] - v;
        int a = base + excl;
        int node = (b << BSH) + t;
        if (node < N) {
            rse[node]  = make_int2(a, a + v);
            dinv[node] = rsqrtf((float)v + 1.0f);
            atomicAdd(&ldh[v > 63 ? 63 : v], 1);   // LDS histogram
        }
        cnt[t] = a;                            // cursor
    }
    __syncthreads();
    if (t < 64 && ldh[t]) atomicAdd(&dhist[t], ldh[t]);  // 1 add/bin/block
    for (int i = base + t; i < end; i += 1024) {
        u32 p = pairs[i];
        int pos = atomicAdd(&cnt[p & (BNODES - 1)], 1);
        col[pos] = (int)((p >> BSH) << 7);     // byte offset = src * 128
    }
}

// degree-sort scatter: nmap = node ids sorted by (clamped) degree.
// Block-aggregated (R12 lesson): LDS histogram -> ONE global span
// reservation per bin per block (dcnt2) -> local cursor scatter.
// nmap is a permutation of [0,N); intra-bin order arbitrary -> per-node
// results bit-identical regardless.
__global__ void __launch_bounds__(256) dscat_k(
        const int2* __restrict__ rse, const int* __restrict__ dhist,
        int* __restrict__ dcnt2, int* __restrict__ nmap, int N) {
    __shared__ int dbase[64];
    __shared__ int ldh[64];
    __shared__ int lspan[64];
    __shared__ int lcur[64];
    int t = threadIdx.x;
    if (t < 64) {
        int v = dhist[t];
        int x = v;
        for (int off = 1; off < 64; off <<= 1) {
            int y = __shfl_up(x, off, 64);
            if (t >= off) x += y;
        }
        dbase[t] = x - v;                     // exclusive prefix over bins
        ldh[t] = 0; lcur[t] = 0;
    }
    __syncthreads();
    int i = blockIdx.x * 256 + t;
    int d = -1;
    if (i < N) {
        int2 se = rse[i];
        d = se.y - se.x; if (d > 63) d = 63;
        atomicAdd(&ldh[d], 1);                // LDS histogram
    }
    __syncthreads();
    if (t < 64) lspan[t] = ldh[t] ? atomicAdd(&dcnt2[t], ldh[t]) : 0;  // reserve
    __syncthreads();
    if (i < N) {
        int off = atomicAdd(&lcur[d], 1);     // LDS cursor
        nmap[dbase[d] + lspan[d] + off] = i;
    }
}

// full-grid layer-1 transform: h1' = (x @ W1) * dinv -> bf16 rows into hp
// (hp aliases the pairs buffer; safe across the kernel boundary).
__global__ void __launch_bounds__(256) gemm1_k(
        const float* __restrict__ x, const float* __restrict__ W1,
        const float* __restrict__ dinv, u16* __restrict__ hp, int N) {
    __shared__ float Wl[DIN * DH];           // 8 KB
    __shared__ float xl[16][DIN + 4];        // 2.3 KB
    int t = threadIdx.x;
    {
        const float4* Wv = (const float4*)W1;
        float4* Wd = (float4*)Wl;
        #pragma unroll
        for (int r = 0; r < 2; r++) Wd[t + 256 * r] = Wv[t + 256 * r];
    }
    // zero hp sentinel row (index N): read by agg_gemm_k's sentinel gathers.
    if (blockIdx.x == 0 && t < 32)
        ((float*)(hp + (size_t)N * DH))[t] = 0.f;
    if (t < 128) {
        int row = t >> 3, ck = (t & 7) * 4;
        int node = blockIdx.x * 16 + row;
        float4 vx = {0.f, 0.f, 0.f, 0.f};
        if (node < N)
            vx = *(const float4*)&x[(size_t)node * DIN + ck];
        *(float4*)&xl[row][ck] = vx;
    }
    __syncthreads();
    int lane = t & 63, w = t >> 6;
    int g = lane >> 4, c = lane & 15;
    int nl = w * 4 + g;
    int node = blockIdx.x * 16 + nl;
    const float* xr = xl[nl];
    float4 acc = {0.f, 0.f, 0.f, 0.f};
    #pragma unroll
    for (int k = 0; k < DIN; k++) {
        float xv = xr[k];
        float4 wv = *(const float4*)&Wl[k * DH + c * 4];
        acc.x += xv * wv.x; acc.y += xv * wv.y; acc.z += xv * wv.z; acc.w += xv * wv.w;
    }
    if (node < N) {
        float di = dinv[node];
        ushort4 o;
        o.x = f2bf(acc.x * di); o.y = f2bf(acc.y * di);
        o.z = f2bf(acc.z * di); o.w = f2bf(acc.w * di);
        *(ushort4*)&hp[(size_t)node * DH + c * 4] = o;
    }
}

// group-per-node edge sum, 8-lane groups: lane c (0..7) owns 8 columns (16B).
// ROLLING depth-8 (R9/R10-proven): accumulate v[j] (oldest) then immediately
// reissue v[j] for the next chunk -> ~8-14 loads in flight with only 32
// buffer VGPRs. Byte-offset cols, folded lane offset, sentinel row.
// Per-column accumulation order is edge-ascending.
__device__ __forceinline__ void edge_sum_roll8(const u16* __restrict__ hp,
                                               const int* __restrict__ colb,
                                               int start, int deg, int gl, int c,
                                               int sentb, f32x2* __restrict__ acc) {
    int dm = deg;                              // wave-uniform max degree
    dm = max(dm, __shfl_xor(dm, 8, 64));
    dm = max(dm, __shfl_xor(dm, 16, 64));
    dm = max(dm, __shfl_xor(dm, 32, 64));
    if (dm <= 0) return;
    const char* hpco = (const char*)hp + ((u32)c << 4);
    int nch = (dm + 7) >> 3;
    uint4 v0, v1, v2, v3, v4, v5, v6, v7;
    int cb = (c < deg) ? colb[start + c] : sentb;     // chunk 0 col slice
    {   // prologue: issue chunk 0
        int s;
        s = __shfl(cb, gl | 0, 64); v0 = *(const uint4*)(hpco + s);
        s = __shfl(cb, gl | 1, 64); v1 = *(const uint4*)(hpco + s);
        s = __shfl(cb, gl | 2, 64); v2 = *(const uint4*)(hpco + s);
        s = __shfl(cb, gl | 3, 64); v3 = *(const uint4*)(hpco + s);
        s = __shfl(cb, gl | 4, 64); v4 = *(const uint4*)(hpco + s);
        s = __shfl(cb, gl | 5, 64); v5 = *(const uint4*)(hpco + s);
        s = __shfl(cb, gl | 6, 64); v6 = *(const uint4*)(hpco + s);
        s = __shfl(cb, gl | 7, 64); v7 = *(const uint4*)(hpco + s);
    }
    int cbn = (8 + c < deg) ? colb[start + 8 + c] : sentb;   // chunk 1 cols
    for (int ch = 1; ch < nch; ch++) {
        int cbu = cbn;
        int nb2 = (ch + 1) << 3;
        cbn = (nb2 + c < deg) ? colb[start + nb2 + c] : sentb;  // prefetch ahead
        int s;
        s = __shfl(cbu, gl | 0, 64);
        pkacc(acc[0], v0.x); pkacc(acc[1], v0.y); pkacc(acc[2], v0.z); pkacc(acc[3], v0.w);
        v0 = *(const uint4*)(hpco + s);
        s = __shfl(cbu, gl | 1, 64);
        pkacc(acc[0], v1.x); pkacc(acc[1], v1.y); pkacc(acc[2], v1.z); pkacc(acc[3], v1.w);
        v1 = *(const uint4*)(hpco + s);
        s = __shfl(cbu, gl | 2, 64);
        pkacc(acc[0], v2.x); pkacc(acc[1], v2.y); pkacc(acc[2], v2.z); pkacc(acc[3], v2.w);
        v2 = *(const uint4*)(hpco + s);
        s = __shfl(cbu, gl | 3, 64);
        pkacc(acc[0], v3.x); pkacc(acc[1], v3.y); pkacc(acc[2], v3.z); pkacc(acc[3], v3.w);
        v3 = *(const uint4*)(hpco + s);
        s = __shfl(cbu, gl | 4, 64);
        pkacc(acc[0], v4.x); pkacc(acc[1], v4.y); pkacc(acc[2], v4.z); pkacc(acc[3], v4.w);
        v4 = *(const uint4*)(hpco + s);
        s = __shfl(cbu, gl | 5, 64);
        pkacc(acc[0], v5.x); pkacc(acc[1], v5.y); pkacc(acc[2], v5.z); pkacc(acc[3], v5.w);
        v5 = *(const uint4*)(hpco + s);
        s = __shfl(cbu, gl | 6, 64);
        pkacc(acc[0], v6.x); pkacc(acc[1], v6.y); pkacc(acc[2], v6.z); pkacc(acc[3], v6.w);
        v6 = *(const uint4*)(hpco + s);
        s = __shfl(cbu, gl | 7, 64);
        pkacc(acc[0], v7.x); pkacc(acc[1], v7.y); pkacc(acc[2], v7.z); pkacc(acc[3], v7.w);
        v7 = *(const uint4*)(hpco + s);
    }
    // drain final chunk
    pkacc(acc[0], v0.x); pkacc(acc[1], v0.y); pkacc(acc[2], v0.z); pkacc(acc[3], v0.w);
    pkacc(acc[0], v1.x); pkacc(acc[1], v1.y); pkacc(acc[2], v1.z); pkacc(acc[3], v1.w);
    pkacc(acc[0], v2.x); pkacc(acc[1], v2.y); pkacc(acc[2], v2.z); pkacc(acc[3], v2.w);
    pkacc(acc[0], v3.x); pkacc(acc[1], v3.y); pkacc(acc[2], v3.z); pkacc(acc[3], v3.w);
    pkacc(acc[0], v4.x); pkacc(acc[1], v4.y); pkacc(acc[2], v4.z); pkacc(acc[3], v4.w);
    pkacc(acc[0], v5.x); pkacc(acc[1], v5.y); pkacc(acc[2], v5.z); pkacc(acc[3], v5.w);
    pkacc(acc[0], v6.x); pkacc(acc[1], v6.y); pkacc(acc[2], v6.z); pkacc(acc[3], v6.w);
    pkacc(acc[0], v7.x); pkacc(acc[1], v7.y); pkacc(acc[2], v7.z); pkacc(acc[3], v7.w);
}

// FUSED layer-1 aggregation + layer-2 GEMM: roll8 gather + xs-LDS epilogue
// (R10-proven) + degree-sorted node remap: all 8 nodes of a wave have
// near-equal degree -> wave-max padding eliminated.
__global__ void __launch_bounds__(256) agg_gemm_k(
        const u16* __restrict__ hp, const int2* __restrict__ rse,
        const int* __restrict__ col, const int* __restrict__ nmap,
        const float* __restrict__ dinv, const float* __restrict__ b1,
        const float* __restrict__ W2, u16* __restrict__ hp2, int N) {
    __shared__ float Wl[DH * DH];            // 16 KB
    __shared__ float xs[4][8][DH + 4];       // 8.5 KB, group rows, 68-float stride
    int tid = threadIdx.x;
    {
        const float4* Wv = (const float4*)W2;
        float4* Wd = (float4*)Wl;
        #pragma unroll
        for (int r = 0; r < 4; r++) Wd[tid + 256 * r] = Wv[tid + 256 * r];
    }
    // zero hp2's sentinel row (read by agg_head_k next kernel; hp2 != hp)
    if (blockIdx.x == 0 && tid < 32)
        ((float*)(hp2 + (size_t)N * DH))[tid] = 0.f;
    __syncthreads();
    int lane = tid & 63, w = tid >> 6;
    int g = lane >> 3, c = lane & 7, gl = g << 3;
    int idx = blockIdx.x * 32 + w * 8 + g;
    int node = (idx < N) ? nmap[idx] : N;     // N -> deg 0, all guards false
    int start = 0, deg = 0;
    if (node < N) { int2 se = rse[node]; start = se.x; deg = se.y - se.x; }
    f32x2 acc[4] = {{0.f,0.f},{0.f,0.f},{0.f,0.f},{0.f,0.f}};
    edge_sum_roll8(hp, col, start, deg, gl, c, N << 7, acc);
    float di = (node < N) ? dinv[node] : 0.f;
    float o0=0.f,o1=0.f,o2=0.f,o3=0.f,o4=0.f,o5=0.f,o6=0.f,o7=0.f;
    if (node < N) {
        uint4 sv = *(const uint4*)&hp[(size_t)node * DH + c * 8];
        float4 blo = *(const float4*)&b1[c * 8];
        float4 bhi = *(const float4*)&b1[c * 8 + 4];
        o0 = fmaxf((acc[0][0] + bfl(sv.x)) * di + blo.x, 0.f);
        o1 = fmaxf((acc[0][1] + bfh(sv.x)) * di + blo.y, 0.f);
        o2 = fmaxf((acc[1][0] + bfl(sv.y)) * di + blo.z, 0.f);
        o3 = fmaxf((acc[1][1] + bfh(sv.y)) * di + blo.w, 0.f);
        o4 = fmaxf((acc[2][0] + bfl(sv.z)) * di + bhi.x, 0.f);
        o5 = fmaxf((acc[2][1] + bfh(sv.z)) * di + bhi.y, 0.f);
        o6 = fmaxf((acc[3][0] + bfl(sv.w)) * di + bhi.z, 0.f);
        o7 = fmaxf((acc[3][1] + bfh(sv.w)) * di + bhi.w, 0.f);
    }
    *(float4*)&xs[w][g][c * 8]     = make_float4(o0, o1, o2, o3);  // same-wave
    *(float4*)&xs[w][g][c * 8 + 4] = make_float4(o4, o5, o6, o7);  // produce/consume
    const float* xr = xs[w][g];
    float4 alo = {0.f,0.f,0.f,0.f}, ahi = {0.f,0.f,0.f,0.f};
    #pragma unroll
    for (int k4 = 0; k4 < DH / 4; k4++) {
        float4 xv4 = *(const float4*)&xr[k4 * 4];
        float xj[4] = {xv4.x, xv4.y, xv4.z, xv4.w};
        #pragma unroll
        for (int j = 0; j < 4; j++) {
            const float* wr = &Wl[(k4 * 4 + j) * DH + c * 8];
            float4 w0 = *(const float4*)wr;
            float4 w1 = *(const float4*)(wr + 4);
            float xv = xj[j];
            alo.x += xv * w0.x; alo.y += xv * w0.y; alo.z += xv * w0.z; alo.w += xv * w0.w;
            ahi.x += xv * w1.x; ahi.y += xv * w1.y; ahi.z += xv * w1.z; ahi.w += xv * w1.w;
        }
    }
    if (node < N) {
        uint4 po;
        po.x = (u32)f2bf(alo.x * di) | ((u32)f2bf(alo.y * di) << 16);
        po.y = (u32)f2bf(alo.z * di) | ((u32)f2bf(alo.w * di) << 16);
        po.z = (u32)f2bf(ahi.x * di) | ((u32)f2bf(ahi.y * di) << 16);
        po.w = (u32)f2bf(ahi.z * di) | ((u32)f2bf(ahi.w * di) << 16);
        *(uint4*)&hp2[(size_t)node * DH + c * 8] = po;
    }
}

// fused layer-2 aggregation + head: y = sigmoid(relu(out2) . Wo + bo)
// roll8 gather + degree-sorted node remap.
__global__ void __launch_bounds__(256) agg_head_k(
        const u16* __restrict__ hp, const int2* __restrict__ rse,
        const int* __restrict__ col, const int* __restrict__ nmap,
        const float* __restrict__ dinv, const float* __restrict__ bias,
        const float* __restrict__ Wo, const float* __restrict__ bo,
        float* __restrict__ y, int N) {
    int lane = threadIdx.x & 63;
    int g = lane >> 3, c = lane & 7, gl = g << 3;
    int idx = blockIdx.x * 32 + (threadIdx.x >> 6) * 8 + g;
    int node = (idx < N) ? nmap[idx] : N;
    int start = 0, deg = 0;
    if (node < N) { int2 se = rse[node]; start = se.x; deg = se.y - se.x; }
    f32x2 acc[4] = {{0.f,0.f},{0.f,0.f},{0.f,0.f},{0.f,0.f}};
    edge_sum_roll8(hp, col, start, deg, gl, c, N << 7, acc);
    float t = 0.f;
    if (node < N) {
        uint4 sv = *(const uint4*)&hp[(size_t)node * DH + c * 8];
        float4 blo = *(const float4*)&bias[c * 8];
        float4 bhi = *(const float4*)&bias[c * 8 + 4];
        float4 wlo = *(const float4*)&Wo[c * 8];
        float4 whi = *(const float4*)&Wo[c * 8 + 4];
        float di = dinv[node];
        t = fmaxf((acc[0][0] + bfl(sv.x)) * di + blo.x, 0.f) * wlo.x
          + fmaxf((acc[0][1] + bfh(sv.x)) * di + blo.y, 0.f) * wlo.y
          + fmaxf((acc[1][0] + bfl(sv.y)) * di + blo.z, 0.f) * wlo.z
          + fmaxf((acc[1][1] + bfh(sv.y)) * di + blo.w, 0.f) * wlo.w
          + fmaxf((acc[2][0] + bfl(sv.z)) * di + bhi.x, 0.f) * whi.x
          + fmaxf((acc[2][1] + bfh(sv.z)) * di + bhi.y, 0.f) * whi.y
          + fmaxf((acc[3][0] + bfl(sv.w)) * di + bhi.z, 0.f) * whi.z
          + fmaxf((acc[3][1] + bfh(sv.w)) * di + bhi.w, 0.f) * whi.w;
    }
    t += __shfl_xor(t, 1, 64);
    t += __shfl_xor(t, 2, 64);
    t += __shfl_xor(t, 4, 64);
    if (c == 0 && node < N) {
        float z = t + bo[0];
        y[node] = 1.f / (1.f + __expf(-z));
    }
}

extern "C" void kernel_launch(void* const* d_in, const int* in_sizes, int n_in,
                              void* d_out, int out_size, void* d_ws, size_t ws_size,
                              hipStream_t stream) {
    const float* x  = (const float*)d_in[0];
    const int*   ei = (const int*)d_in[1];
    const float* W1 = (const float*)d_in[2];
    const float* b1 = (const float*)d_in[3];
    const float* W2 = (const float*)d_in[4];
    const float* b2 = (const float*)d_in[5];
    const float* Wo = (const float*)d_in[6];
    const float* bo = (const float*)d_in[7];
    float* y = (float*)d_out;

    int N = in_sizes[0] / DIN;
    int E = in_sizes[1] / 2;
    int nbuck = ((N - 1) >> BSH) + 1;            // 391 for N=100k (<= MAXB)

    char* ws = (char*)d_ws;
    size_t off = 0;
    auto alloc = [&](size_t bytes) { char* p = ws + off; off += (bytes + 255) & ~(size_t)255; return p; };
    int*   gcnt   = (int*)alloc((MAXB + 128) * 4);   // + dhist[64] + dcnt2[64]
    int*   dhist  = gcnt + MAXB;
    int*   dcnt2  = gcnt + MAXB + 64;
    int2*  rse    = (int2*)alloc((size_t)N * 8);
    float* dinv   = (float*)alloc((size_t)N * 4);
    int*   nmap   = (int*)alloc((size_t)N * 4);
    int*   col    = (int*)alloc(((size_t)nbuck << CAPSH) * 4);   // ~12.8 MB
    size_t pair_b = ((size_t)nbuck << CAPSH) * 4;
    size_t hp_b   = (size_t)N * DH * 2 + 256;                    // + zero sentinel row
    char*  bufA   = (char*)alloc(pair_b > hp_b ? pair_b : hp_b); // pairs / h1' alias
    u16*   bufB   = (u16*)alloc(hp_b);                           // h2' bf16 + sentinel
    u16*   hp    = (u16*)bufA;
    u32*   pairs = (u32*)bufA;

    hipMemsetAsync(gcnt, 0, (size_t)(MAXB + 128) * 4, stream);
    binA_k<<<256, 1024, 0, stream>>>(ei, gcnt, pairs, E, N, nbuck);
    // CSR build (pairs consumed; col = byte offsets; LDS-agg degree hist)
    csr_build_k<<<nbuck, 1024, 0, stream>>>(pairs, gcnt, rse, col, dinv, dhist, N);
    // degree-sorted node remap (block-aggregated span reservation)
    dscat_k<<<(N + 255) / 256, 256, 0, stream>>>(rse, dhist, dcnt2, nmap, N);
    // full-grid layer-1 transform (overwrites pairs span with h1' bf16)
    gemm1_k<<<(N + 15) / 16, 256, 0, stream>>>(x, W1, dinv, hp, N);
    // layer-1 aggregation fused with layer-2 transform: bufB = h2'
    agg_gemm_k<<<(N + 31) / 32, 256, 0, stream>>>(hp, rse, col, nmap, dinv, b1, W2, bufB, N);
    // layer-2 aggregation fused with head
    agg_head_k<<<(N + 31) / 32, 256, 0, stream>>>(bufB, rse, col, nmap, dinv, b2, Wo, bo, y, N);
}

// Round 14
// 194.495 us; speedup vs baseline: 3.6335x; 1.0211x over previous
//
#include <hip/hip_runtime.h>

#define DH 64
#define DIN 32
#define BSH 8                 // bucket = dst >> 8 (256-node ranges)
#define BNODES 256
#define MAXB 1024
#define CAPSH 13              // per-bucket capacity 8192 (avg fill ~4.1k, sigma ~64)
#define CAP (1 << CAPSH)

typedef unsigned short u16;
typedef unsigned int u32;
typedef float f32x2 __attribute__((ext_vector_type(2)));

__device__ __forceinline__ float bf2f(u16 u) {
    union { u32 i; float f; } x; x.i = ((u32)u) << 16; return x.f;
}
__device__ __forceinline__ u16 f2bf(float f) {
    union { float f; u32 i; } x; x.f = f;
    u32 r = x.i + 0x7fff + ((x.i >> 16) & 1);    // round-to-nearest-even
    return (u16)(r >> 16);
}
// unpack low/high bf16 of a u32 (2 packed bf16) to f32
__device__ __forceinline__ float bfl(u32 u) {
    union { u32 i; float f; } x; x.i = u << 16; return x.f;
}
__device__ __forceinline__ float bfh(u32 u) {
    union { u32 i; float f; } x; x.i = u & 0xffff0000u; return x.f;
}
// packed-f32 accumulate of 2 bf16 lanes: a += {bfl(u), bfh(u)}
__device__ __forceinline__ void pkacc(f32x2& a, u32 u) {
    f32x2 b;
    b[0] = bfl(u); b[1] = bfh(u);
    asm("v_pk_add_f32 %0, %1, %0" : "+v"(a) : "v"(b));
}

// bin packed (src<<BSH | local_dst) into fixed-capacity bucket spans with
// per-(block,bucket) private sub-spans. Grid-stride granules.
// 256 blocks x 1024 thr: ~16 edges = 64B block-private sectors (R7's
// false-sharing lesson: keep spans >= one 64B sector and block-private).
__global__ void __launch_bounds__(1024) binA_k(
        const int* __restrict__ ei, int* __restrict__ gcnt,
        u32* __restrict__ pairs, int E, int n, int nbuck) {
    __shared__ int lhist[MAXB];
    __shared__ int lbase[MAXB];
    __shared__ int smode;
    int t = threadIdx.x;
    if (t < 64) {   // int64 layout: odd 32-bit words are zero high-words
        int v = (2 * t + 1 < 2 * E) ? ei[2 * t + 1] : 0;
        unsigned long long b = __ballot(v != 0);
        if (t == 0) smode = (b != 0ULL) ? 1 : 0;
    }
    for (int b = t; b < nbuck; b += 1024) lhist[b] = 0;
    __syncthreads();
    int m = smode;
    unsigned un = (unsigned)n;
    int q0 = blockIdx.x * 1024 + t;
    int qs = gridDim.x * 1024;

    // ---- phase 1: count this block's edges per bucket
    if (m && !(E & 3)) {                       // int32, 4 edges per int4
        const int4* d4 = (const int4*)(ei + E);
        for (int q = q0; q < (E >> 2); q += qs) {
            int4 d = d4[q];
            if ((unsigned)d.x < un) atomicAdd(&lhist[d.x >> BSH], 1);
            if ((unsigned)d.y < un) atomicAdd(&lhist[d.y >> BSH], 1);
            if ((unsigned)d.z < un) atomicAdd(&lhist[d.z >> BSH], 1);
            if ((unsigned)d.w < un) atomicAdd(&lhist[d.w >> BSH], 1);
        }
    } else if (!m && !(E & 1)) {               // int64, 2 edges per int4
        const int4* d4 = (const int4*)(ei + 2 * E);
        for (int q = q0; q < (E >> 1); q += qs) {
            int4 d = d4[q];
            if ((unsigned)d.x < un) atomicAdd(&lhist[d.x >> BSH], 1);
            if ((unsigned)d.z < un) atomicAdd(&lhist[d.z >> BSH], 1);
        }
    } else {
        const int* dstp = m ? (ei + E) : (ei + 2 * E);
        int stride = m ? 1 : 2;
        for (int e = q0; e < E; e += qs) {
            int d = dstp[(size_t)e * stride];
            if ((unsigned)d < un) atomicAdd(&lhist[d >> BSH], 1);
        }
    }
    __syncthreads();
    // ---- phase 2: reserve private spans
    for (int b = t; b < nbuck; b += 1024) {
        int c = lhist[b];
        lbase[b] = c ? ((b << CAPSH) + atomicAdd(&gcnt[b], c)) : 0;
        lhist[b] = 0;                          // reuse as local cursor
    }
    __syncthreads();
    // ---- phase 3: scatter into private spans
    #define EMIT(S, D)                                                     \
        if ((unsigned)(D) < un) {                                          \
            int sv = ((unsigned)(S) < un) ? (S) : 0;                       \
            int bb = (D) >> BSH;                                           \
            int off = atomicAdd(&lhist[bb], 1);                            \
            int pos = lbase[bb] + off;                                     \
            if (pos < ((bb + 1) << CAPSH))                                 \
                pairs[pos] = ((u32)sv << BSH) | (u32)((D) & (BNODES - 1)); \
        }
    if (m && !(E & 3)) {
        const int4* s4 = (const int4*)ei;
        const int4* d4 = (const int4*)(ei + E);
        for (int q = q0; q < (E >> 2); q += qs) {
            int4 s = s4[q]; int4 d = d4[q];
            EMIT(s.x, d.x) EMIT(s.y, d.y) EMIT(s.z, d.z) EMIT(s.w, d.w)
        }
    } else if (!m && !(E & 1)) {
        const int4* s4 = (const int4*)ei;
        const int4* d4 = (const int4*)(ei + 2 * E);
        for (int q = q0; q < (E >> 1); q += qs) {
            int4 s = s4[q]; int4 d = d4[q];
            EMIT(s.x, d.x) EMIT(s.z, d.z)
        }
    } else {
        const int* srcp = ei;
        const int* dstp = m ? (ei + E) : (ei + 2 * E);
        int stride = m ? 1 : 2;
        for (int e = q0; e < E; e += qs) {
            int d = dstp[(size_t)e * stride];
            int s = srcp[(size_t)e * stride];
            EMIT(s, d)
        }
    }
    #undef EMIT
}

// one block (1024 thr) per bucket: CSR build, two-pass (R10-proven), plus a
// WINDOWED degree-sort: the bucket's (<=256) nodes are counting-sorted by
// clamped degree into nmap[(b<<8)..], entirely in LDS. Wave's 8 nodes then
// have near-equal degree (padding fix) while staying in the SAME bucket
// (col spans + hp rows stay in a 32KB window — the locality R13's global
// sort destroyed). nmap is a permutation of [0,N); per-node accumulation
// order unchanged -> bit-identical results.
__global__ void __launch_bounds__(1024) csr_build_k(
        const u32* __restrict__ pairs, const int* __restrict__ gcnt,
        int2* __restrict__ rse,
        int* __restrict__ col, float* __restrict__ dinv,
        int* __restrict__ nmap, int N) {
    __shared__ int cnt[BNODES];
    __shared__ int s[BNODES];
    __shared__ int db[64];
    int b = blockIdx.x, t = threadIdx.x;
    int base = b << CAPSH;
    int ec = gcnt[b]; if (ec > CAP) ec = CAP;
    int end = base + ec;
    if (t < BNODES) cnt[t] = 0;
    if (t < 64) db[t] = 0;
    __syncthreads();
    for (int i = base + t; i < end; i += 1024)
        atomicAdd(&cnt[pairs[i] & (BNODES - 1)], 1);
    __syncthreads();
    int v = (t < BNODES) ? cnt[t] : 0;
    if (t < BNODES) s[t] = v;
    __syncthreads();
    for (int off = 1; off < BNODES; off <<= 1) {
        int xsc = (t >= off && t < BNODES) ? s[t - off] : 0;
        __syncthreads();
        if (t < BNODES) s[t] += xsc;
        __syncthreads();
    }
    int node = (b << BSH) + t;
    int dcl = v > 63 ? 63 : v;
    if (t < BNODES) {
        int excl = s[t] - v;
        int a = base + excl;
        if (node < N) {
            rse[node]  = make_int2(a, a + v);
            dinv[node] = rsqrtf((float)v + 1.0f);
            atomicAdd(&db[dcl], 1);            // degree histogram (LDS)
        }
        cnt[t] = a;                            // cursor
    }
    __syncthreads();
    if (t < 64) {                              // wave 0: exclusive bin scan
        int vv = db[t];
        int x = vv;
        for (int off = 1; off < 64; off <<= 1) {
            int y = __shfl_up(x, off, 64);
            if (t >= off) x += y;
        }
        db[t] = x - vv;                        // reuse as base+cursor
    }
    __syncthreads();
    if (t < BNODES && node < N) {
        int pos = atomicAdd(&db[dcl], 1);      // LDS cursor scatter
        nmap[(b << BSH) + pos] = node;
    }
    __syncthreads();
    for (int i = base + t; i < end; i += 1024) {
        u32 p = pairs[i];
        int pos = atomicAdd(&cnt[p & (BNODES - 1)], 1);
        col[pos] = (int)((p >> BSH) << 7);     // byte offset = src * 128
    }
}

// full-grid layer-1 transform: h1' = (x @ W1) * dinv -> bf16 rows into hp
// (hp aliases the pairs buffer; safe across the kernel boundary).
__global__ void __launch_bounds__(256) gemm1_k(
        const float* __restrict__ x, const float* __restrict__ W1,
        const float* __restrict__ dinv, u16* __restrict__ hp, int N) {
    __shared__ float Wl[DIN * DH];           // 8 KB
    __shared__ float xl[16][DIN + 4];        // 2.3 KB
    int t = threadIdx.x;
    {
        const float4* Wv = (const float4*)W1;
        float4* Wd = (float4*)Wl;
        #pragma unroll
        for (int r = 0; r < 2; r++) Wd[t + 256 * r] = Wv[t + 256 * r];
    }
    // zero hp sentinel row (index N): read by agg_gemm_k's sentinel gathers.
    if (blockIdx.x == 0 && t < 32)
        ((float*)(hp + (size_t)N * DH))[t] = 0.f;
    if (t < 128) {
        int row = t >> 3, ck = (t & 7) * 4;
        int node = blockIdx.x * 16 + row;
        float4 vx = {0.f, 0.f, 0.f, 0.f};
        if (node < N)
            vx = *(const float4*)&x[(size_t)node * DIN + ck];
        *(float4*)&xl[row][ck] = vx;
    }
    __syncthreads();
    int lane = t & 63, w = t >> 6;
    int g = lane >> 4, c = lane & 15;
    int nl = w * 4 + g;
    int node = blockIdx.x * 16 + nl;
    const float* xr = xl[nl];
    float4 acc = {0.f, 0.f, 0.f, 0.f};
    #pragma unroll
    for (int k = 0; k < DIN; k++) {
        float xv = xr[k];
        float4 wv = *(const float4*)&Wl[k * DH + c * 4];
        acc.x += xv * wv.x; acc.y += xv * wv.y; acc.z += xv * wv.z; acc.w += xv * wv.w;
    }
    if (node < N) {
        float di = dinv[node];
        ushort4 o;
        o.x = f2bf(acc.x * di); o.y = f2bf(acc.y * di);
        o.z = f2bf(acc.z * di); o.w = f2bf(acc.w * di);
        *(ushort4*)&hp[(size_t)node * DH + c * 4] = o;
    }
}

// group-per-node edge sum, 8-lane groups: lane c (0..7) owns 8 columns (16B).
// ROLLING depth-8 (R9/R10-proven): accumulate v[j] (oldest) then immediately
// reissue v[j] for the next chunk -> ~8-14 loads in flight with only 32
// buffer VGPRs. Byte-offset cols, folded lane offset, sentinel row.
// Per-column accumulation order is edge-ascending.
__device__ __forceinline__ void edge_sum_roll8(const u16* __restrict__ hp,
                                               const int* __restrict__ colb,
                                               int start, int deg, int gl, int c,
                                               int sentb, f32x2* __restrict__ acc) {
    int dm = deg;                              // wave-uniform max degree
    dm = max(dm, __shfl_xor(dm, 8, 64));
    dm = max(dm, __shfl_xor(dm, 16, 64));
    dm = max(dm, __shfl_xor(dm, 32, 64));
    if (dm <= 0) return;
    const char* hpco = (const char*)hp + ((u32)c << 4);
    int nch = (dm + 7) >> 3;
    uint4 v0, v1, v2, v3, v4, v5, v6, v7;
    int cb = (c < deg) ? colb[start + c] : sentb;     // chunk 0 col slice
    {   // prologue: issue chunk 0
        int s;
        s = __shfl(cb, gl | 0, 64); v0 = *(const uint4*)(hpco + s);
        s = __shfl(cb, gl | 1, 64); v1 = *(const uint4*)(hpco + s);
        s = __shfl(cb, gl | 2, 64); v2 = *(const uint4*)(hpco + s);
        s = __shfl(cb, gl | 3, 64); v3 = *(const uint4*)(hpco + s);
        s = __shfl(cb, gl | 4, 64); v4 = *(const uint4*)(hpco + s);
        s = __shfl(cb, gl | 5, 64); v5 = *(const uint4*)(hpco + s);
        s = __shfl(cb, gl | 6, 64); v6 = *(const uint4*)(hpco + s);
        s = __shfl(cb, gl | 7, 64); v7 = *(const uint4*)(hpco + s);
    }
    int cbn = (8 + c < deg) ? colb[start + 8 + c] : sentb;   // chunk 1 cols
    for (int ch = 1; ch < nch; ch++) {
        int cbu = cbn;
        int nb2 = (ch + 1) << 3;
        cbn = (nb2 + c < deg) ? colb[start + nb2 + c] : sentb;  // prefetch ahead
        int s;
        s = __shfl(cbu, gl | 0, 64);
        pkacc(acc[0], v0.x); pkacc(acc[1], v0.y); pkacc(acc[2], v0.z); pkacc(acc[3], v0.w);
        v0 = *(const uint4*)(hpco + s);
        s = __shfl(cbu, gl | 1, 64);
        pkacc(acc[0], v1.x); pkacc(acc[1], v1.y); pkacc(acc[2], v1.z); pkacc(acc[3], v1.w);
        v1 = *(const uint4*)(hpco + s);
        s = __shfl(cbu, gl | 2, 64);
        pkacc(acc[0], v2.x); pkacc(acc[1], v2.y); pkacc(acc[2], v2.z); pkacc(acc[3], v2.w);
        v2 = *(const uint4*)(hpco + s);
        s = __shfl(cbu, gl | 3, 64);
        pkacc(acc[0], v3.x); pkacc(acc[1], v3.y); pkacc(acc[2], v3.z); pkacc(acc[3], v3.w);
        v3 = *(const uint4*)(hpco + s);
        s = __shfl(cbu, gl | 4, 64);
        pkacc(acc[0], v4.x); pkacc(acc[1], v4.y); pkacc(acc[2], v4.z); pkacc(acc[3], v4.w);
        v4 = *(const uint4*)(hpco + s);
        s = __shfl(cbu, gl | 5, 64);
        pkacc(acc[0], v5.x); pkacc(acc[1], v5.y); pkacc(acc[2], v5.z); pkacc(acc[3], v5.w);
        v5 = *(const uint4*)(hpco + s);
        s = __shfl(cbu, gl | 6, 64);
        pkacc(acc[0], v6.x); pkacc(acc[1], v6.y); pkacc(acc[2], v6.z); pkacc(acc[3], v6.w);
        v6 = *(const uint4*)(hpco + s);
        s = __shfl(cbu, gl | 7, 64);
        pkacc(acc[0], v7.x); pkacc(acc[1], v7.y); pkacc(acc[2], v7.z); pkacc(acc[3], v7.w);
        v7 = *(const uint4*)(hpco + s);
    }
    // drain final chunk
    pkacc(acc[0], v0.x); pkacc(acc[1], v0.y); pkacc(acc[2], v0.z); pkacc(acc[3], v0.w);
    pkacc(acc[0], v1.x); pkacc(acc[1], v1.y); pkacc(acc[2], v1.z); pkacc(acc[3], v1.w);
    pkacc(acc[0], v2.x); pkacc(acc[1], v2.y); pkacc(acc[2], v2.z); pkacc(acc[3], v2.w);
    pkacc(acc[0], v3.x); pkacc(acc[1], v3.y); pkacc(acc[2], v3.z); pkacc(acc[3], v3.w);
    pkacc(acc[0], v4.x); pkacc(acc[1], v4.y); pkacc(acc[2], v4.z); pkacc(acc[3], v4.w);
    pkacc(acc[0], v5.x); pkacc(acc[1], v5.y); pkacc(acc[2], v5.z); pkacc(acc[3], v5.w);
    pkacc(acc[0], v6.x); pkacc(acc[1], v6.y); pkacc(acc[2], v6.z); pkacc(acc[3], v6.w);
    pkacc(acc[0], v7.x); pkacc(acc[1], v7.y); pkacc(acc[2], v7.z); pkacc(acc[3], v7.w);
}

// FUSED layer-1 aggregation + layer-2 GEMM: roll8 gather + xs-LDS epilogue
// (R10-proven) + windowed degree-sorted node remap (same-bucket waves).
__global__ void __launch_bounds__(256) agg_gemm_k(
        const u16* __restrict__ hp, const int2* __restrict__ rse,
        const int* __restrict__ col, const int* __restrict__ nmap,
        const float* __restrict__ dinv, const float* __restrict__ b1,
        const float* __restrict__ W2, u16* __restrict__ hp2, int N) {
    __shared__ float Wl[DH * DH];            // 16 KB
    __shared__ float xs[4][8][DH + 4];       // 8.5 KB, group rows, 68-float stride
    int tid = threadIdx.x;
    {
        const float4* Wv = (const float4*)W2;
        float4* Wd = (float4*)Wl;
        #pragma unroll
        for (int r = 0; r < 4; r++) Wd[tid + 256 * r] = Wv[tid + 256 * r];
    }
    // zero hp2's sentinel row (read by agg_head_k next kernel; hp2 != hp)
    if (blockIdx.x == 0 && tid < 32)
        ((float*)(hp2 + (size_t)N * DH))[tid] = 0.f;
    __syncthreads();
    int lane = tid & 63, w = tid >> 6;
    int g = lane >> 3, c = lane & 7, gl = g << 3;
    int idx = blockIdx.x * 32 + w * 8 + g;
    int node = (idx < N) ? nmap[idx] : N;     // N -> deg 0, all guards false
    int start = 0, deg = 0;
    if (node < N) { int2 se = rse[node]; start = se.x; deg = se.y - se.x; }
    f32x2 acc[4] = {{0.f,0.f},{0.f,0.f},{0.f,0.f},{0.f,0.f}};
    edge_sum_roll8(hp, col, start, deg, gl, c, N << 7, acc);
    float di = (node < N) ? dinv[node] : 0.f;
    float o0=0.f,o1=0.f,o2=0.f,o3=0.f,o4=0.f,o5=0.f,o6=0.f,o7=0.f;
    if (node < N) {
        uint4 sv = *(const uint4*)&hp[(size_t)node * DH + c * 8];
        float4 blo = *(const float4*)&b1[c * 8];
        float4 bhi = *(const float4*)&b1[c * 8 + 4];
        o0 = fmaxf((acc[0][0] + bfl(sv.x)) * di + blo.x, 0.f);
        o1 = fmaxf((acc[0][1] + bfh(sv.x)) * di + blo.y, 0.f);
        o2 = fmaxf((acc[1][0] + bfl(sv.y)) * di + blo.z, 0.f);
        o3 = fmaxf((acc[1][1] + bfh(sv.y)) * di + blo.w, 0.f);
        o4 = fmaxf((acc[2][0] + bfl(sv.z)) * di + bhi.x, 0.f);
        o5 = fmaxf((acc[2][1] + bfh(sv.z)) * di + bhi.y, 0.f);
        o6 = fmaxf((acc[3][0] + bfl(sv.w)) * di + bhi.z, 0.f);
        o7 = fmaxf((acc[3][1] + bfh(sv.w)) * di + bhi.w, 0.f);
    }
    *(float4*)&xs[w][g][c * 8]     = make_float4(o0, o1, o2, o3);  // same-wave
    *(float4*)&xs[w][g][c * 8 + 4] = make_float4(o4, o5, o6, o7);  // produce/consume
    const float* xr = xs[w][g];
    float4 alo = {0.f,0.f,0.f,0.f}, ahi = {0.f,0.f,0.f,0.f};
    #pragma unroll
    for (int k4 = 0; k4 < DH / 4; k4++) {
        float4 xv4 = *(const float4*)&xr[k4 * 4];
        float xj[4] = {xv4.x, xv4.y, xv4.z, xv4.w};
        #pragma unroll
        for (int j = 0; j < 4; j++) {
            const float* wr = &Wl[(k4 * 4 + j) * DH + c * 8];
            float4 w0 = *(const float4*)wr;
            float4 w1 = *(const float4*)(wr + 4);
            float xv = xj[j];
            alo.x += xv * w0.x; alo.y += xv * w0.y; alo.z += xv * w0.z; alo.w += xv * w0.w;
            ahi.x += xv * w1.x; ahi.y += xv * w1.y; ahi.z += xv * w1.z; ahi.w += xv * w1.w;
        }
    }
    if (node < N) {
        uint4 po;
        po.x = (u32)f2bf(alo.x * di) | ((u32)f2bf(alo.y * di) << 16);
        po.y = (u32)f2bf(alo.z * di) | ((u32)f2bf(alo.w * di) << 16);
        po.z = (u32)f2bf(ahi.x * di) | ((u32)f2bf(ahi.y * di) << 16);
        po.w = (u32)f2bf(ahi.z * di) | ((u32)f2bf(ahi.w * di) << 16);
        *(uint4*)&hp2[(size_t)node * DH + c * 8] = po;
    }
}

// fused layer-2 aggregation + head: y = sigmoid(relu(out2) . Wo + bo)
// roll8 gather + windowed degree-sorted node remap.
__global__ void __launch_bounds__(256) agg_head_k(
        const u16* __restrict__ hp, const int2* __restrict__ rse,
        const int* __restrict__ col, const int* __restrict__ nmap,
        const float* __restrict__ dinv, const float* __restrict__ bias,
        const float* __restrict__ Wo, const float* __restrict__ bo,
        float* __restrict__ y, int N) {
    int lane = threadIdx.x & 63;
    int g = lane >> 3, c = lane & 7, gl = g << 3;
    int idx = blockIdx.x * 32 + (threadIdx.x >> 6) * 8 + g;
    int node = (idx < N) ? nmap[idx] : N;
    int start = 0, deg = 0;
    if (node < N) { int2 se = rse[node]; start = se.x; deg = se.y - se.x; }
    f32x2 acc[4] = {{0.f,0.f},{0.f,0.f},{0.f,0.f},{0.f,0.f}};
    edge_sum_roll8(hp, col, start, deg, gl, c, N << 7, acc);
    float t = 0.f;
    if (node < N) {
        uint4 sv = *(const uint4*)&hp[(size_t)node * DH + c * 8];
        float4 blo = *(const float4*)&bias[c * 8];
        float4 bhi = *(const float4*)&bias[c * 8 + 4];
        float4 wlo = *(const float4*)&Wo[c * 8];
        float4 whi = *(const float4*)&Wo[c * 8 + 4];
        float di = dinv[node];
        t = fmaxf((acc[0][0] + bfl(sv.x)) * di + blo.x, 0.f) * wlo.x
          + fmaxf((acc[0][1] + bfh(sv.x)) * di + blo.y, 0.f) * wlo.y
          + fmaxf((acc[1][0] + bfl(sv.y)) * di + blo.z, 0.f) * wlo.z
          + fmaxf((acc[1][1] + bfh(sv.y)) * di + blo.w, 0.f) * wlo.w
          + fmaxf((acc[2][0] + bfl(sv.z)) * di + bhi.x, 0.f) * whi.x
          + fmaxf((acc[2][1] + bfh(sv.z)) * di + bhi.y, 0.f) * whi.y
          + fmaxf((acc[3][0] + bfl(sv.w)) * di + bhi.z, 0.f) * whi.z
          + fmaxf((acc[3][1] + bfh(sv.w)) * di + bhi.w, 0.f) * whi.w;
    }
    t += __shfl_xor(t, 1, 64);
    t += __shfl_xor(t, 2, 64);
    t += __shfl_xor(t, 4, 64);
    if (c == 0 && node < N) {
        float z = t + bo[0];
        y[node] = 1.f / (1.f + __expf(-z));
    }
}

extern "C" void kernel_launch(void* const* d_in, const int* in_sizes, int n_in,
                              void* d_out, int out_size, void* d_ws, size_t ws_size,
                              hipStream_t stream) {
    const float* x  = (const float*)d_in[0];
    const int*   ei = (const int*)d_in[1];
    const float* W1 = (const float*)d_in[2];
    const float* b1 = (const float*)d_in[3];
    const float* W2 = (const float*)d_in[4];
    const float* b2 = (const float*)d_in[5];
    const float* Wo = (const float*)d_in[6];
    const float* bo = (const float*)d_in[7];
    float* y = (float*)d_out;

    int N = in_sizes[0] / DIN;
    int E = in_sizes[1] / 2;
    int nbuck = ((N - 1) >> BSH) + 1;            // 391 for N=100k (<= MAXB)

    char* ws = (char*)d_ws;
    size_t off = 0;
    auto alloc = [&](size_t bytes) { char* p = ws + off; off += (bytes + 255) & ~(size_t)255; return p; };
    int*   gcnt   = (int*)alloc(MAXB * 4);
    int2*  rse    = (int2*)alloc((size_t)N * 8);
    float* dinv   = (float*)alloc((size_t)N * 4);
    int*   nmap   = (int*)alloc((size_t)N * 4);
    int*   col    = (int*)alloc(((size_t)nbuck << CAPSH) * 4);   // ~12.8 MB
    size_t pair_b = ((size_t)nbuck << CAPSH) * 4;
    size_t hp_b   = (size_t)N * DH * 2 + 256;                    // + zero sentinel row
    char*  bufA   = (char*)alloc(pair_b > hp_b ? pair_b : hp_b); // pairs / h1' alias
    u16*   bufB   = (u16*)alloc(hp_b);                           // h2' bf16 + sentinel
    u16*   hp    = (u16*)bufA;
    u32*   pairs = (u32*)bufA;

    hipMemsetAsync(gcnt, 0, (size_t)MAXB * 4, stream);
    binA_k<<<256, 1024, 0, stream>>>(ei, gcnt, pairs, E, N, nbuck);
    // CSR build (pairs consumed; col = byte offsets; windowed degree-sort)
    csr_build_k<<<nbuck, 1024, 0, stream>>>(pairs, gcnt, rse, col, dinv, nmap, N);
    // full-grid layer-1 transform (overwrites pairs span with h1' bf16)
    gemm1_k<<<(N + 15) / 16, 256, 0, stream>>>(x, W1, dinv, hp, N);
    // layer-1 aggregation fused with layer-2 transform: bufB = h2'
    agg_gemm_k<<<(N + 31) / 32, 256, 0, stream>>>(hp, rse, col, nmap, dinv, b1, W2, bufB, N);
    // layer-2 aggregation fused with head
    agg_head_k<<<(N + 31) / 32, 256, 0, stream>>>(bufB, rse, col, nmap, dinv, b2, Wo, bo, y, N);
}

// Round 15
// 179.859 us; speedup vs baseline: 3.9292x; 1.0814x over previous
//
#include <hip/hip_runtime.h>

#define DH 64
#define DIN 32
#define BSH 8                 // bucket = dst >> 8 (256-node ranges)
#define BNODES 256
#define MAXB 1024
#define CAPSH 13              // per-bucket capacity 8192 (avg fill ~4.1k, sigma ~64)
#define CAP (1 << CAPSH)

typedef unsigned short u16;
typedef unsigned int u32;
typedef float f32x2 __attribute__((ext_vector_type(2)));

__device__ __forceinline__ float bf2f(u16 u) {
    union { u32 i; float f; } x; x.i = ((u32)u) << 16; return x.f;
}
__device__ __forceinline__ u16 f2bf(float f) {
    union { float f; u32 i; } x; x.f = f;
    u32 r = x.i + 0x7fff + ((x.i >> 16) & 1);    // round-to-nearest-even
    return (u16)(r >> 16);
}
// unpack low/high bf16 of a u32 (2 packed bf16) to f32
__device__ __forceinline__ float bfl(u32 u) {
    union { u32 i; float f; } x; x.i = u << 16; return x.f;
}
__device__ __forceinline__ float bfh(u32 u) {
    union { u32 i; float f; } x; x.i = u & 0xffff0000u; return x.f;
}
// packed-f32 accumulate of 2 bf16 lanes: a += {bfl(u), bfh(u)}
__device__ __forceinline__ void pkacc(f32x2& a, u32 u) {
    f32x2 b;
    b[0] = bfl(u); b[1] = bfh(u);
    asm("v_pk_add_f32 %0, %1, %0" : "+v"(a) : "v"(b));
}

// bin packed (src<<BSH | local_dst) into fixed-capacity bucket spans with
// per-(block,bucket) private sub-spans. Grid-stride granules.
// 256 blocks x 1024 thr: ~16 edges = 64B block-private sectors (R7's
// false-sharing lesson: keep spans >= one 64B sector and block-private).
__global__ void __launch_bounds__(1024) binA_k(
        const int* __restrict__ ei, int* __restrict__ gcnt,
        u32* __restrict__ pairs, int E, int n, int nbuck) {
    __shared__ int lhist[MAXB];
    __shared__ int lbase[MAXB];
    __shared__ int smode;
    int t = threadIdx.x;
    if (t < 64) {   // int64 layout: odd 32-bit words are zero high-words
        int v = (2 * t + 1 < 2 * E) ? ei[2 * t + 1] : 0;
        unsigned long long b = __ballot(v != 0);
        if (t == 0) smode = (b != 0ULL) ? 1 : 0;
    }
    for (int b = t; b < nbuck; b += 1024) lhist[b] = 0;
    __syncthreads();
    int m = smode;
    unsigned un = (unsigned)n;
    int q0 = blockIdx.x * 1024 + t;
    int qs = gridDim.x * 1024;

    // ---- phase 1: count this block's edges per bucket
    if (m && !(E & 3)) {                       // int32, 4 edges per int4
        const int4* d4 = (const int4*)(ei + E);
        for (int q = q0; q < (E >> 2); q += qs) {
            int4 d = d4[q];
            if ((unsigned)d.x < un) atomicAdd(&lhist[d.x >> BSH], 1);
            if ((unsigned)d.y < un) atomicAdd(&lhist[d.y >> BSH], 1);
            if ((unsigned)d.z < un) atomicAdd(&lhist[d.z >> BSH], 1);
            if ((unsigned)d.w < un) atomicAdd(&lhist[d.w >> BSH], 1);
        }
    } else if (!m && !(E & 1)) {               // int64, 2 edges per int4
        const int4* d4 = (const int4*)(ei + 2 * E);
        for (int q = q0; q < (E >> 1); q += qs) {
            int4 d = d4[q];
            if ((unsigned)d.x < un) atomicAdd(&lhist[d.x >> BSH], 1);
            if ((unsigned)d.z < un) atomicAdd(&lhist[d.z >> BSH], 1);
        }
    } else {
        const int* dstp = m ? (ei + E) : (ei + 2 * E);
        int stride = m ? 1 : 2;
        for (int e = q0; e < E; e += qs) {
            int d = dstp[(size_t)e * stride];
            if ((unsigned)d < un) atomicAdd(&lhist[d >> BSH], 1);
        }
    }
    __syncthreads();
    // ---- phase 2: reserve private spans
    for (int b = t; b < nbuck; b += 1024) {
        int c = lhist[b];
        lbase[b] = c ? ((b << CAPSH) + atomicAdd(&gcnt[b], c)) : 0;
        lhist[b] = 0;                          // reuse as local cursor
    }
    __syncthreads();
    // ---- phase 3: scatter into private spans
    #define EMIT(S, D)                                                     \
        if ((unsigned)(D) < un) {                                          \
            int sv = ((unsigned)(S) < un) ? (S) : 0;                       \
            int bb = (D) >> BSH;                                           \
            int off = atomicAdd(&lhist[bb], 1);                            \
            int pos = lbase[bb] + off;                                     \
            if (pos < ((bb + 1) << CAPSH))                                 \
                pairs[pos] = ((u32)sv << BSH) | (u32)((D) & (BNODES - 1)); \
        }
    if (m && !(E & 3)) {
        const int4* s4 = (const int4*)ei;
        const int4* d4 = (const int4*)(ei + E);
        for (int q = q0; q < (E >> 2); q += qs) {
            int4 s = s4[q]; int4 d = d4[q];
            EMIT(s.x, d.x) EMIT(s.y, d.y) EMIT(s.z, d.z) EMIT(s.w, d.w)
        }
    } else if (!m && !(E & 1)) {
        const int4* s4 = (const int4*)ei;
        const int4* d4 = (const int4*)(ei + 2 * E);
        for (int q = q0; q < (E >> 1); q += qs) {
            int4 s = s4[q]; int4 d = d4[q];
            EMIT(s.x, d.x) EMIT(s.z, d.z)
        }
    } else {
        const int* srcp = ei;
        const int* dstp = m ? (ei + E) : (ei + 2 * E);
        int stride = m ? 1 : 2;
        for (int e = q0; e < E; e += qs) {
            int d = dstp[(size_t)e * stride];
            int s = srcp[(size_t)e * stride];
            EMIT(s, d)
        }
    }
    #undef EMIT
}

// one block (1024 thr) per bucket: CSR build, two-pass (R10-proven).
// col[] stores PRE-SHIFTED byte offsets (src * 128);
// rse[node] = {start, end} packed int2.
__global__ void __launch_bounds__(1024) csr_build_k(
        const u32* __restrict__ pairs, const int* __restrict__ gcnt,
        int2* __restrict__ rse,
        int* __restrict__ col, float* __restrict__ dinv, int N) {
    __shared__ int cnt[BNODES];
    __shared__ int s[BNODES];
    int b = blockIdx.x, t = threadIdx.x;
    int base = b << CAPSH;
    int ec = gcnt[b]; if (ec > CAP) ec = CAP;
    int end = base + ec;
    if (t < BNODES) cnt[t] = 0;
    __syncthreads();
    for (int i = base + t; i < end; i += 1024)
        atomicAdd(&cnt[pairs[i] & (BNODES - 1)], 1);
    __syncthreads();
    int v = (t < BNODES) ? cnt[t] : 0;
    if (t < BNODES) s[t] = v;
    __syncthreads();
    for (int off = 1; off < BNODES; off <<= 1) {
        int xsc = (t >= off && t < BNODES) ? s[t - off] : 0;
        __syncthreads();
        if (t < BNODES) s[t] += xsc;
        __syncthreads();
    }
    if (t < BNODES) {
        int excl = s[t] - v;
        int a = base + excl;
        int node = (b << BSH) + t;
        if (node < N) {
            rse[node]  = make_int2(a, a + v);
            dinv[node] = rsqrtf((float)v + 1.0f);
        }
        cnt[t] = a;                            // cursor
    }
    __syncthreads();
    for (int i = base + t; i < end; i += 1024) {
        u32 p = pairs[i];
        int pos = atomicAdd(&cnt[p & (BNODES - 1)], 1);
        col[pos] = (int)((p >> BSH) << 7);     // byte offset = src * 128
    }
}

// full-grid layer-1 transform: h1' = (x @ W1) * dinv -> bf16 rows into hp
// (hp aliases the pairs buffer; safe across the kernel boundary).
__global__ void __launch_bounds__(256) gemm1_k(
        const float* __restrict__ x, const float* __restrict__ W1,
        const float* __restrict__ dinv, u16* __restrict__ hp, int N) {
    __shared__ float Wl[DIN * DH];           // 8 KB
    __shared__ float xl[16][DIN + 4];        // 2.3 KB
    int t = threadIdx.x;
    {
        const float4* Wv = (const float4*)W1;
        float4* Wd = (float4*)Wl;
        #pragma unroll
        for (int r = 0; r < 2; r++) Wd[t + 256 * r] = Wv[t + 256 * r];
    }
    // zero hp sentinel row (index N): read by agg_gemm_k's sentinel gathers.
    if (blockIdx.x == 0 && t < 32)
        ((float*)(hp + (size_t)N * DH))[t] = 0.f;
    if (t < 128) {
        int row = t >> 3, ck = (t & 7) * 4;
        int node = blockIdx.x * 16 + row;
        float4 vx = {0.f, 0.f, 0.f, 0.f};
        if (node < N)
            vx = *(const float4*)&x[(size_t)node * DIN + ck];
        *(float4*)&xl[row][ck] = vx;
    }
    __syncthreads();
    int lane = t & 63, w = t >> 6;
    int g = lane >> 4, c = lane & 15;
    int nl = w * 4 + g;
    int node = blockIdx.x * 16 + nl;
    const float* xr = xl[nl];
    float4 acc = {0.f, 0.f, 0.f, 0.f};
    #pragma unroll
    for (int k = 0; k < DIN; k++) {
        float xv = xr[k];
        float4 wv = *(const float4*)&Wl[k * DH + c * 4];
        acc.x += xv * wv.x; acc.y += xv * wv.y; acc.z += xv * wv.z; acc.w += xv * wv.w;
    }
    if (node < N) {
        float di = dinv[node];
        ushort4 o;
        o.x = f2bf(acc.x * di); o.y = f2bf(acc.y * di);
        o.z = f2bf(acc.z * di); o.w = f2bf(acc.w * di);
        *(ushort4*)&hp[(size_t)node * DH + c * 4] = o;
    }
}

// group-per-node edge sum, 8-lane groups: lane c (0..7) owns 8 columns (16B).
// ROLLING depth-8 (R9/R10-proven): accumulate v[j] (oldest) then immediately
// reissue v[j] for the next chunk -> ~8-14 loads in flight with only 32
// buffer VGPRs. Byte-offset cols, folded lane offset, sentinel row.
// Per-column accumulation order is edge-ascending.
__device__ __forceinline__ void edge_sum_roll8(const u16* __restrict__ hp,
                                               const int* __restrict__ colb,
                                               int start, int deg, int gl, int c,
                                               int sentb, f32x2* __restrict__ acc) {
    int dm = deg;                              // wave-uniform max degree
    dm = max(dm, __shfl_xor(dm, 8, 64));
    dm = max(dm, __shfl_xor(dm, 16, 64));
    dm = max(dm, __shfl_xor(dm, 32, 64));
    if (dm <= 0) return;
    const char* hpco = (const char*)hp + ((u32)c << 4);
    int nch = (dm + 7) >> 3;
    uint4 v0, v1, v2, v3, v4, v5, v6, v7;
    int cb = (c < deg) ? colb[start + c] : sentb;     // chunk 0 col slice
    {   // prologue: issue chunk 0
        int s;
        s = __shfl(cb, gl | 0, 64); v0 = *(const uint4*)(hpco + s);
        s = __shfl(cb, gl | 1, 64); v1 = *(const uint4*)(hpco + s);
        s = __shfl(cb, gl | 2, 64); v2 = *(const uint4*)(hpco + s);
        s = __shfl(cb, gl | 3, 64); v3 = *(const uint4*)(hpco + s);
        s = __shfl(cb, gl | 4, 64); v4 = *(const uint4*)(hpco + s);
        s = __shfl(cb, gl | 5, 64); v5 = *(const uint4*)(hpco + s);
        s = __shfl(cb, gl | 6, 64); v6 = *(const uint4*)(hpco + s);
        s = __shfl(cb, gl | 7, 64); v7 = *(const uint4*)(hpco + s);
    }
    int cbn = (8 + c < deg) ? colb[start + 8 + c] : sentb;   // chunk 1 cols
    for (int ch = 1; ch < nch; ch++) {
        int cbu = cbn;
        int nb2 = (ch + 1) << 3;
        cbn = (nb2 + c < deg) ? colb[start + nb2 + c] : sentb;  // prefetch ahead
        int s;
        s = __shfl(cbu, gl | 0, 64);
        pkacc(acc[0], v0.x); pkacc(acc[1], v0.y); pkacc(acc[2], v0.z); pkacc(acc[3], v0.w);
        v0 = *(const uint4*)(hpco + s);
        s = __shfl(cbu, gl | 1, 64);
        pkacc(acc[0], v1.x); pkacc(acc[1], v1.y); pkacc(acc[2], v1.z); pkacc(acc[3], v1.w);
        v1 = *(const uint4*)(hpco + s);
        s = __shfl(cbu, gl | 2, 64);
        pkacc(acc[0], v2.x); pkacc(acc[1], v2.y); pkacc(acc[2], v2.z); pkacc(acc[3], v2.w);
        v2 = *(const uint4*)(hpco + s);
        s = __shfl(cbu, gl | 3, 64);
        pkacc(acc[0], v3.x); pkacc(acc[1], v3.y); pkacc(acc[2], v3.z); pkacc(acc[3], v3.w);
        v3 = *(const uint4*)(hpco + s);
        s = __shfl(cbu, gl | 4, 64);
        pkacc(acc[0], v4.x); pkacc(acc[1], v4.y); pkacc(acc[2], v4.z); pkacc(acc[3], v4.w);
        v4 = *(const uint4*)(hpco + s);
        s = __shfl(cbu, gl | 5, 64);
        pkacc(acc[0], v5.x); pkacc(acc[1], v5.y); pkacc(acc[2], v5.z); pkacc(acc[3], v5.w);
        v5 = *(const uint4*)(hpco + s);
        s = __shfl(cbu, gl | 6, 64);
        pkacc(acc[0], v6.x); pkacc(acc[1], v6.y); pkacc(acc[2], v6.z); pkacc(acc[3], v6.w);
        v6 = *(const uint4*)(hpco + s);
        s = __shfl(cbu, gl | 7, 64);
        pkacc(acc[0], v7.x); pkacc(acc[1], v7.y); pkacc(acc[2], v7.z); pkacc(acc[3], v7.w);
        v7 = *(const uint4*)(hpco + s);
    }
    // drain final chunk
    pkacc(acc[0], v0.x); pkacc(acc[1], v0.y); pkacc(acc[2], v0.z); pkacc(acc[3], v0.w);
    pkacc(acc[0], v1.x); pkacc(acc[1], v1.y); pkacc(acc[2], v1.z); pkacc(acc[3], v1.w);
    pkacc(acc[0], v2.x); pkacc(acc[1], v2.y); pkacc(acc[2], v2.z); pkacc(acc[3], v2.w);
    pkacc(acc[0], v3.x); pkacc(acc[1], v3.y); pkacc(acc[2], v3.z); pkacc(acc[3], v3.w);
    pkacc(acc[0], v4.x); pkacc(acc[1], v4.y); pkacc(acc[2], v4.z); pkacc(acc[3], v4.w);
    pkacc(acc[0], v5.x); pkacc(acc[1], v5.y); pkacc(acc[2], v5.z); pkacc(acc[3], v5.w);
    pkacc(acc[0], v6.x); pkacc(acc[1], v6.y); pkacc(acc[2], v6.z); pkacc(acc[3], v6.w);
    pkacc(acc[0], v7.x); pkacc(acc[1], v7.y); pkacc(acc[2], v7.z); pkacc(acc[3], v7.w);
}

// FUSED layer-1 aggregation + layer-2 GEMM, 512 threads: 8 waves share the
// 16KB Wl (LDS 33.8KB -> 4 blocks/CU x 8 waves = 32 waves/CU, vs 24 at the
// 256-thread shape). roll8 gather compiles ~48 VGPR (R14) — under the
// 64-VGPR cliff naturally, NO forced bound (R4's spill lesson).
__global__ void __launch_bounds__(512) agg_gemm_k(
        const u16* __restrict__ hp, const int2* __restrict__ rse,
        const int* __restrict__ col,
        const float* __restrict__ dinv, const float* __restrict__ b1,
        const float* __restrict__ W2, u16* __restrict__ hp2, int N) {
    __shared__ float Wl[DH * DH];            // 16 KB (shared by 8 waves)
    __shared__ float xs[8][8][DH + 4];       // 17 KB, group rows, 68-float stride
    int tid = threadIdx.x;
    {
        const float4* Wv = (const float4*)W2;
        float4* Wd = (float4*)Wl;
        #pragma unroll
        for (int r = 0; r < 2; r++) Wd[tid + 512 * r] = Wv[tid + 512 * r];
    }
    // zero hp2's sentinel row (read by agg_head_k next kernel; hp2 != hp)
    if (blockIdx.x == 0 && tid < 32)
        ((float*)(hp2 + (size_t)N * DH))[tid] = 0.f;
    __syncthreads();
    int lane = tid & 63, w = tid >> 6;
    int g = lane >> 3, c = lane & 7, gl = g << 3;
    int node = blockIdx.x * 64 + w * 8 + g;
    int start = 0, deg = 0;
    if (node < N) { int2 se = rse[node]; start = se.x; deg = se.y - se.x; }
    f32x2 acc[4] = {{0.f,0.f},{0.f,0.f},{0.f,0.f},{0.f,0.f}};
    edge_sum_roll8(hp, col, start, deg, gl, c, N << 7, acc);
    float di = (node < N) ? dinv[node] : 0.f;
    float o0=0.f,o1=0.f,o2=0.f,o3=0.f,o4=0.f,o5=0.f,o6=0.f,o7=0.f;
    if (node < N) {
        uint4 sv = *(const uint4*)&hp[(size_t)node * DH + c * 8];
        float4 blo = *(const float4*)&b1[c * 8];
        float4 bhi = *(const float4*)&b1[c * 8 + 4];
        o0 = fmaxf((acc[0][0] + bfl(sv.x)) * di + blo.x, 0.f);
        o1 = fmaxf((acc[0][1] + bfh(sv.x)) * di + blo.y, 0.f);
        o2 = fmaxf((acc[1][0] + bfl(sv.y)) * di + blo.z, 0.f);
        o3 = fmaxf((acc[1][1] + bfh(sv.y)) * di + blo.w, 0.f);
        o4 = fmaxf((acc[2][0] + bfl(sv.z)) * di + bhi.x, 0.f);
        o5 = fmaxf((acc[2][1] + bfh(sv.z)) * di + bhi.y, 0.f);
        o6 = fmaxf((acc[3][0] + bfl(sv.w)) * di + bhi.z, 0.f);
        o7 = fmaxf((acc[3][1] + bfh(sv.w)) * di + bhi.w, 0.f);
    }
    *(float4*)&xs[w][g][c * 8]     = make_float4(o0, o1, o2, o3);  // same-wave
    *(float4*)&xs[w][g][c * 8 + 4] = make_float4(o4, o5, o6, o7);  // produce/consume
    const float* xr = xs[w][g];
    float4 alo = {0.f,0.f,0.f,0.f}, ahi = {0.f,0.f,0.f,0.f};
    #pragma unroll
    for (int k4 = 0; k4 < DH / 4; k4++) {
        float4 xv4 = *(const float4*)&xr[k4 * 4];
        float xj[4] = {xv4.x, xv4.y, xv4.z, xv4.w};
        #pragma unroll
        for (int j = 0; j < 4; j++) {
            const float* wr = &Wl[(k4 * 4 + j) * DH + c * 8];
            float4 w0 = *(const float4*)wr;
            float4 w1 = *(const float4*)(wr + 4);
            float xv = xj[j];
            alo.x += xv * w0.x; alo.y += xv * w0.y; alo.z += xv * w0.z; alo.w += xv * w0.w;
            ahi.x += xv * w1.x; ahi.y += xv * w1.y; ahi.z += xv * w1.z; ahi.w += xv * w1.w;
        }
    }
    if (node < N) {
        uint4 po;
        po.x = (u32)f2bf(alo.x * di) | ((u32)f2bf(alo.y * di) << 16);
        po.y = (u32)f2bf(alo.z * di) | ((u32)f2bf(alo.w * di) << 16);
        po.z = (u32)f2bf(ahi.x * di) | ((u32)f2bf(ahi.y * di) << 16);
        po.w = (u32)f2bf(ahi.z * di) | ((u32)f2bf(ahi.w * di) << 16);
        *(uint4*)&hp2[(size_t)node * DH + c * 8] = po;
    }
}

// fused layer-2 aggregation + head: y = sigmoid(relu(out2) . Wo + bo)
// roll8 gather (R10-proven): 8 waves/SIMD x ~10 deep.
__global__ void __launch_bounds__(256) agg_head_k(
        const u16* __restrict__ hp, const int2* __restrict__ rse,
        const int* __restrict__ col,
        const float* __restrict__ dinv, const float* __restrict__ bias,
        const float* __restrict__ Wo, const float* __restrict__ bo,
        float* __restrict__ y, int N) {
    int lane = threadIdx.x & 63;
    int g = lane >> 3, c = lane & 7, gl = g << 3;
    int node = blockIdx.x * 32 + (threadIdx.x >> 6) * 8 + g;
    int start = 0, deg = 0;
    if (node < N) { int2 se = rse[node]; start = se.x; deg = se.y - se.x; }
    f32x2 acc[4] = {{0.f,0.f},{0.f,0.f},{0.f,0.f},{0.f,0.f}};
    edge_sum_roll8(hp, col, start, deg, gl, c, N << 7, acc);
    float t = 0.f;
    if (node < N) {
        uint4 sv = *(const uint4*)&hp[(size_t)node * DH + c * 8];
        float4 blo = *(const float4*)&bias[c * 8];
        float4 bhi = *(const float4*)&bias[c * 8 + 4];
        float4 wlo = *(const float4*)&Wo[c * 8];
        float4 whi = *(const float4*)&Wo[c * 8 + 4];
        float di = dinv[node];
        t = fmaxf((acc[0][0] + bfl(sv.x)) * di + blo.x, 0.f) * wlo.x
          + fmaxf((acc[0][1] + bfh(sv.x)) * di + blo.y, 0.f) * wlo.y
          + fmaxf((acc[1][0] + bfl(sv.y)) * di + blo.z, 0.f) * wlo.z
          + fmaxf((acc[1][1] + bfh(sv.y)) * di + blo.w, 0.f) * wlo.w
          + fmaxf((acc[2][0] + bfl(sv.z)) * di + bhi.x, 0.f) * whi.x
          + fmaxf((acc[2][1] + bfh(sv.z)) * di + bhi.y, 0.f) * whi.y
          + fmaxf((acc[3][0] + bfl(sv.w)) * di + bhi.z, 0.f) * whi.z
          + fmaxf((acc[3][1] + bfh(sv.w)) * di + bhi.w, 0.f) * whi.w;
    }
    t += __shfl_xor(t, 1, 64);
    t += __shfl_xor(t, 2, 64);
    t += __shfl_xor(t, 4, 64);
    if (c == 0 && node < N) {
        float z = t + bo[0];
        y[node] = 1.f / (1.f + __expf(-z));
    }
}

extern "C" void kernel_launch(void* const* d_in, const int* in_sizes, int n_in,
                              void* d_out, int out_size, void* d_ws, size_t ws_size,
                              hipStream_t stream) {
    const float* x  = (const float*)d_in[0];
    const int*   ei = (const int*)d_in[1];
    const float* W1 = (const float*)d_in[2];
    const float* b1 = (const float*)d_in[3];
    const float* W2 = (const float*)d_in[4];
    const float* b2 = (const float*)d_in[5];
    const float* Wo = (const float*)d_in[6];
    const float* bo = (const float*)d_in[7];
    float* y = (float*)d_out;

    int N = in_sizes[0] / DIN;
    int E = in_sizes[1] / 2;
    int nbuck = ((N - 1) >> BSH) + 1;            // 391 for N=100k (<= MAXB)

    char* ws = (char*)d_ws;
    size_t off = 0;
    auto alloc = [&](size_t bytes) { char* p = ws + off; off += (bytes + 255) & ~(size_t)255; return p; };
    int*   gcnt   = (int*)alloc(MAXB * 4);
    int2*  rse    = (int2*)alloc((size_t)N * 8);
    float* dinv   = (float*)alloc((size_t)N * 4);
    int*   col    = (int*)alloc(((size_t)nbuck << CAPSH) * 4);   // ~12.8 MB
    size_t pair_b = ((size_t)nbuck << CAPSH) * 4;
    size_t hp_b   = (size_t)N * DH * 2 + 256;                    // + zero sentinel row
    char*  bufA   = (char*)alloc(pair_b > hp_b ? pair_b : hp_b); // pairs / h1' alias
    u16*   bufB   = (u16*)alloc(hp_b);                           // h2' bf16 + sentinel
    u16*   hp    = (u16*)bufA;
    u32*   pairs = (u32*)bufA;

    hipMemsetAsync(gcnt, 0, (size_t)MAXB * 4, stream);
    binA_k<<<256, 1024, 0, stream>>>(ei, gcnt, pairs, E, N, nbuck);
    // CSR build (pairs consumed here; col = pre-shifted byte offsets)
    csr_build_k<<<nbuck, 1024, 0, stream>>>(pairs, gcnt, rse, col, dinv, N);
    // full-grid layer-1 transform (overwrites pairs span with h1' bf16)
    gemm1_k<<<(N + 15) / 16, 256, 0, stream>>>(x, W1, dinv, hp, N);
    // layer-1 aggregation fused with layer-2 transform: bufB = h2'
    agg_gemm_k<<<(N + 63) / 64, 512, 0, stream>>>(hp, rse, col, dinv, b1, W2, bufB, N);
    // layer-2 aggregation fused with head
    agg_head_k<<<(N + 31) / 32, 256, 0, stream>>>(bufB, rse, col, dinv, b2, Wo, bo, y, N);
}